// Round 2
// baseline (396.877 us; speedup 1.0000x reference)
//
#include <hip/hip_runtime.h>
#include <cstdint>
#include <cstddef>

// ---------- types ----------
typedef __attribute__((ext_vector_type(8))) short short8;     // 8 x bf16
typedef __attribute__((ext_vector_type(4))) float f32x4;
typedef __attribute__((ext_vector_type(4))) unsigned short ushort4v;

#define DEVI __device__ __forceinline__

DEVI unsigned short f2bf(float f) {  // RNE f32 -> bf16 bits
  union { float f; unsigned u; } x; x.f = f;
  unsigned r = x.u + 0x7fffu + ((x.u >> 16) & 1u);
  return (unsigned short)(r >> 16);
}

#define MFMA16(a, b, c) __builtin_amdgcn_mfma_f32_16x16x32_bf16(a, b, c, 0, 0, 0)
#define FENCE asm volatile("" ::: "memory")
#define WAITVM(n) asm volatile("s_waitcnt vmcnt(" #n ")" ::: "memory")
#define WAITLGKM0 asm volatile("s_waitcnt lgkmcnt(0)" ::: "memory")
#define BARRIER do { FENCE; __builtin_amdgcn_s_barrier(); FENCE; } while (0)

typedef __attribute__((address_space(1))) const void g_void;
typedef __attribute__((address_space(3))) void lds_void;
DEVI void gload_lds16(const void* g, void* l) {
  __builtin_amdgcn_global_load_lds((g_void*)g, (lds_void*)l, 16, 0, 0);
}

// ---------- constants ----------
static constexpr int DM = 1024;   // d_model
static constexpr int NH = 16;     // heads
static constexpr int DK = 64;     // head dim
static constexpr int FF = 4096;   // d_ff
static constexpr int BB = 8;      // batch
static constexpr int LL = 1024;   // seq
static constexpr int TT = BB * LL; // 8192 tokens

// ---------- fused prep: 6 weight cvts + QKV bias concat + mask dtype detect ----
__global__ __launch_bounds__(256) void prep_kernel(
    const float* __restrict__ Wq, const float* __restrict__ Wk,
    const float* __restrict__ Wv, const float* __restrict__ Wo,
    const float* __restrict__ W1, const float* __restrict__ W2,
    const float* __restrict__ bq, const float* __restrict__ bk,
    const float* __restrict__ bv,
    unsigned short* __restrict__ wqkv, unsigned short* __restrict__ wob,
    unsigned short* __restrict__ w1b, unsigned short* __restrict__ w2b,
    float* __restrict__ bqkv, const unsigned* __restrict__ mask,
    int* __restrict__ flag) {
  int b = blockIdx.x;
  if (b < 6144) {
    int i = b * 256 + threadIdx.x;
    const float* src; unsigned short* dst; int li;
    if (i < 131072)      { src = Wq; dst = wqkv;             li = i; }
    else if (i < 262144) { src = Wk; dst = wqkv + (1 << 20); li = i - 131072; }
    else if (i < 393216) { src = Wv; dst = wqkv + (2 << 20); li = i - 262144; }
    else if (i < 524288) { src = Wo; dst = wob;              li = i - 393216; }
    else if (i < 1048576){ src = W1; dst = w1b;              li = i - 524288; }
    else                 { src = W2; dst = w2b;              li = i - 1048576; }
    const f32x4* s4 = (const f32x4*)src;
    f32x4 a = s4[li * 2], c = s4[li * 2 + 1];
    short8 o;
    o[0] = (short)f2bf(a[0]); o[1] = (short)f2bf(a[1]);
    o[2] = (short)f2bf(a[2]); o[3] = (short)f2bf(a[3]);
    o[4] = (short)f2bf(c[0]); o[5] = (short)f2bf(c[1]);
    o[6] = (short)f2bf(c[2]); o[7] = (short)f2bf(c[3]);
    *(short8*)(dst + (size_t)li * 8) = o;
  } else if (b < 6156) {
    int i = (b - 6144) * 256 + threadIdx.x;  // 3072
    bqkv[i] = (i < 1024) ? bq[i] : (i < 2048 ? bk[i - 1024] : bv[i - 2048]);
  } else {
    unsigned a = 0;
    for (int i = threadIdx.x; i < 4096; i += 256) a |= mask[i];
    #pragma unroll
    for (int off = 32; off >= 1; off >>= 1) a |= __shfl_xor(a, off);
    __shared__ unsigned sh[4];
    if ((threadIdx.x & 63) == 0) sh[threadIdx.x >> 6] = a;
    __syncthreads();
    if (threadIdx.x == 0) {
      unsigned o = sh[0] | sh[1] | sh[2] | sh[3];
      flag[0] = (o & 0xFEFEFEFEu) ? 2 : ((o & 0xFFFFFF00u) ? 1 : 0);
    }
  }
}

// ---------- LayerNorm (fp32 in, bf16 out) + optional mask-pack blocks ----------
__global__ __launch_bounds__(256) void ln_kernel(const float* __restrict__ x,
                                                 const float* __restrict__ sc,
                                                 const float* __restrict__ bi,
                                                 unsigned short* __restrict__ out,
                                                 const void* __restrict__ mask,
                                                 unsigned* __restrict__ mp,
                                                 const int* __restrict__ flag,
                                                 int npack) {
  int row = blockIdx.x;
  int t = threadIdx.x;
  if (row >= TT) {
    int w = (row - TT) * 256 + t;   // word over B*L*(L/32) = 262144
    int cls = flag[0];
    unsigned bits = 0u;
    if (cls == 1) {
      const unsigned char* mb = (const unsigned char*)mask + (size_t)w * 32;
      #pragma unroll 8
      for (int i = 0; i < 32; ++i) bits |= (mb[i] ? 1u : 0u) << i;
    } else {
      const unsigned* mi = (const unsigned*)mask + (size_t)w * 32;
      #pragma unroll 8
      for (int i = 0; i < 32; ++i) bits |= (mi[i] ? 1u : 0u) << i;
    }
    mp[w] = bits;
    return;
  }
  const f32x4* xr = (const f32x4*)(x + (size_t)row * DM);
  f32x4 v = xr[t];
  float s = v[0] + v[1] + v[2] + v[3];
  float q = v[0]*v[0] + v[1]*v[1] + v[2]*v[2] + v[3]*v[3];
  #pragma unroll
  for (int off = 32; off >= 1; off >>= 1) { s += __shfl_xor(s, off); q += __shfl_xor(q, off); }
  __shared__ float red[8];
  int wv = t >> 6;
  if ((t & 63) == 0) { red[wv] = s; red[4 + wv] = q; }
  __syncthreads();
  s = red[0] + red[1] + red[2] + red[3];
  q = red[4] + red[5] + red[6] + red[7];
  float mu = s * (1.0f / DM);
  float var = q * (1.0f / DM) - mu * mu;
  float rs = rsqrtf(var + 1e-5f);
  f32x4 sv = ((const f32x4*)sc)[t], bv = ((const f32x4*)bi)[t];
  ushort4v o;
  #pragma unroll
  for (int j = 0; j < 4; ++j) o[j] = f2bf((v[j] - mu) * rs * sv[j] + bv[j]);
  *(ushort4v*)(out + (size_t)row * DM + t * 4) = o;
}

// ---------- GEMM v9: 128x128, dbuf pipelined, 2 blocks/CU (kept for N=1024) ----
template <int EPI>
__global__ __launch_bounds__(256, 2)
void gemm5(const unsigned short* __restrict__ A, const unsigned short* __restrict__ Bw,
           const float* __restrict__ bias, void* __restrict__ out0,
           void* __restrict__ out1, void* __restrict__ out2,
           const float* __restrict__ res, int N, int K) {
  __shared__ __align__(16) char smem[65536];  // 2 x 32KB
  const int t = threadIdx.x;
  const int w = t >> 6, ln = t & 63;
  const int wm = w >> 1, wn = w & 1;
  const int lg = ln >> 4, lc = ln & 15;
  const int m0 = blockIdx.x * 128, n0 = blockIdx.y * 128;
  const size_t rb = (size_t)K * 2;
  const int nk = K >> 6;

  const char* srcp[8];
  #pragma unroll
  for (int i = 0; i < 8; ++i) {
    int off = i * 4096 + t * 16;
    if (off < 16384) {
      int r = off >> 7, c = (off >> 4) & 7;
      srcp[i] = (const char*)A + (size_t)(m0 + r) * rb + ((c ^ (r & 7)) << 4);
    } else {
      int ob = off - 16384;
      int r = ob >> 7, c = (ob >> 4) & 7;
      srcp[i] = (const char*)Bw + (size_t)(n0 + r) * rb + ((c ^ (r & 7)) << 4);
    }
  }
  auto stage8 = [&](int tile) {
    char* db = smem + ((tile & 1) << 15) + t * 16;
    const size_t ko = (size_t)tile << 7;
    #pragma unroll
    for (int i = 0; i < 8; ++i) gload_lds16(srcp[i] + ko, db + i * 4096);
  };

  int aoff[4][2], boff[4][2];
  #pragma unroll
  for (int x_ = 0; x_ < 4; ++x_)
    #pragma unroll
    for (int kk = 0; kk < 2; ++kk) {
      int ra = wm * 64 + x_ * 16 + lc;
      aoff[x_][kk] = ra * 128 + (((kk * 4 + lg) ^ (ra & 7)) << 4);
      int rn = wn * 64 + x_ * 16 + lc;
      boff[x_][kk] = 16384 + rn * 128 + (((kk * 4 + lg) ^ (rn & 7)) << 4);
    }

  f32x4 acc[4][4] = {};

  stage8(0);
  for (int T = 0; T < nk; ++T) {
    if (T + 1 < nk) stage8(T + 1);
    if (T == nk - 1) { WAITVM(0); } else { WAITVM(8); }  // tile T landed
    BARRIER;
    const char* buf = smem + ((T & 1) << 15);
    short8 afr[4][2], bfr[4][2];
    #pragma unroll
    for (int ni = 0; ni < 4; ++ni) {
      bfr[ni][0] = *(const short8*)(buf + boff[ni][0]);
      bfr[ni][1] = *(const short8*)(buf + boff[ni][1]);
    }
    #pragma unroll
    for (int mi = 0; mi < 4; ++mi) {
      afr[mi][0] = *(const short8*)(buf + aoff[mi][0]);
      afr[mi][1] = *(const short8*)(buf + aoff[mi][1]);
    }
    __builtin_amdgcn_s_setprio(1);
    #pragma unroll
    for (int mi = 0; mi < 4; ++mi)
      #pragma unroll
      for (int ni = 0; ni < 4; ++ni) {
        acc[mi][ni] = MFMA16(afr[mi][0], bfr[ni][0], acc[mi][ni]);
        acc[mi][ni] = MFMA16(afr[mi][1], bfr[ni][1], acc[mi][ni]);
      }
    __builtin_amdgcn_s_setprio(0);
    WAITLGKM0;
    BARRIER;
  }
  __syncthreads();

  const int colb = n0 + wn * 64 + lc;
  const int rowb = m0 + wm * 64 + lg * 4;
  if constexpr (EPI >= 2) {
    #pragma unroll
    for (int ni = 0; ni < 4; ++ni) {
      int col = colb + ni * 16;
      float bv = bias[col];
      #pragma unroll
      for (int mi = 0; mi < 4; ++mi)
        #pragma unroll
        for (int rr = 0; rr < 4; ++rr) {
          int row = rowb + mi * 16 + rr;
          float v = acc[mi][ni][rr] + bv;
          if constexpr (EPI == 2)
            ((float*)out0)[(size_t)row * N + col] = res[(size_t)row * N + col] + v;
          else
            ((float*)out0)[(size_t)row * N + col] += v;
        }
    }
  } else {
    short* sl = (short*)(smem + w * 9216);
    const bool isV = (EPI == 0) && (n0 + wn * 64 >= 2048);
    #pragma unroll
    for (int ni = 0; ni < 4; ++ni) {
      float bv = bias[colb + ni * 16];
      #pragma unroll
      for (int mi = 0; mi < 4; ++mi)
        #pragma unroll
        for (int rr = 0; rr < 4; ++rr) {
          int row_l = mi * 16 + lg * 4 + rr;
          int col_l = ni * 16 + lc;
          float v = acc[mi][ni][rr] + bv;
          if constexpr (EPI == 1) {
            float u2 = v * v;
            float mexp = v * (-2.302206744f - 0.102953795f * u2);
            v = v / (1.0f + exp2f(mexp));
          }
          if (isV) sl[col_l * 72 + row_l] = (short)f2bf(v);
          else     sl[row_l * 72 + col_l] = (short)f2bf(v);
        }
    }
    const int s8 = ln >> 3, c8 = ln & 7;
    if constexpr (EPI == 0) {
      const int b_ = m0 >> 10;
      const int l0 = (m0 & 1023) + wm * 64;
      const int h_ = ((n0 + wn * 64) >> 6) & 15;
      const size_t bh = (size_t)(b_ * NH + h_);
      if (n0 + wn * 64 < 2048) {
        char* dst = (char*)((n0 + wn * 64 < 1024) ? out0 : out1) + (((bh << 10) + l0) << 7);
        #pragma unroll
        for (int j = 0; j < 8; ++j) {
          short8 v8 = *(const short8*)(sl + (j * 8 + s8) * 72 + c8 * 8);
          *(short8*)(dst + j * 1024 + ln * 16) = v8;
        }
      } else {
        char* dst = (char*)out2 + bh * 131072 + l0 * 2 + c8 * 16;
        #pragma unroll
        for (int j = 0; j < 8; ++j) {
          short8 v8 = *(const short8*)(sl + (j * 8 + s8) * 72 + c8 * 8);
          *(short8*)(dst + (size_t)(j * 8 + s8) * 2048) = v8;
        }
      }
    } else {
      char* dst = (char*)out0 + (size_t)(m0 + wm * 64) * ((size_t)N * 2) +
                  (size_t)(n0 + wn * 64) * 2 + c8 * 16;
      #pragma unroll
      for (int j = 0; j < 8; ++j) {
        short8 v8 = *(const short8*)(sl + (j * 8 + s8) * 72 + c8 * 8);
        *(short8*)(dst + (size_t)(j * 8 + s8) * ((size_t)N * 2)) = v8;
      }
    }
  }
}

// ---------- GEMM v10b: 256x256 8-phase counted-vmcnt (m201 template) ---------
// 512 thr = 8 waves (2M x 4N), wave tile 128x64, BK=64, LDS 2 x 64KB dbuf.
// launch_bounds (512,1): LDS=128KB already forces 1 block/CU; capping VGPRs at
// 128 (the round-1 (512,2) mistake) spilled the 128-reg accumulator to scratch
// (FETCH +70MB, MfmaUtil 27%). Budget is 256 VGPR/wave at 2 waves/SIMD.
// Per K-tile: 4 phases {ds_read subtile || issue half-tile stage -> barrier ->
// lgkmcnt(0) -> setprio(1) 16 MFMA setprio(0) -> barrier}. Quadrant order
// (M0N0,M1N0,M0N1,M1N1); A frags held in regs across N-halves so A-LDS is
// free after ph1, B after ph2. Staging: ph0 -> (T+1).B1, ph2 -> (T+2).A0,
// ph3 -> (T+2).A1 + (T+2).B0; tile-boundary wait = vmcnt(6) (3 newest
// half-tiles stay in flight across the barrier; never drains to 0 mid-loop).
// EPI 0: fused QKV routing (Q/K -> [B,H,L,dk], V -> [B,H,dk,L]);
// EPI 1: tanh-GELU -> bf16 [M,N]. Requires M%256==0, N%256==0, K%64==0, K>=128.
template <int EPI>
__global__ __launch_bounds__(512, 1)
void gemm8(const unsigned short* __restrict__ A, const unsigned short* __restrict__ Bw,
           const float* __restrict__ bias, void* __restrict__ out0,
           void* __restrict__ out1, void* __restrict__ out2, int N, int K) {
  __shared__ __align__(16) char smem[131072];  // 2 x (A 32KB | B 32KB)
  const int t = threadIdx.x;
  const int w = t >> 6, ln = t & 63;
  const int wm = w >> 2, wn = w & 3;           // 2M x 4N waves
  const int lg = ln >> 4, lc = ln & 15;

  // bijective XCD swizzle (all our grids have nwg % 8 == 0)
  const int gx = gridDim.x;
  const int nwg = gx * gridDim.y;
  int bid = blockIdx.y * gx + blockIdx.x;
  if ((nwg & 7) == 0) bid = (bid & 7) * (nwg >> 3) + (bid >> 3);
  const int m0 = (bid % gx) * 256, n0 = (bid / gx) * 256;

  const int nk = K >> 6;

  // staging: 8 slots of 8KB per tile ([A0 A1 | B0 B1] halves, 2 slots each);
  // LDS dest linear (slot*8192 + t*16), global source pre-XOR-swizzled by row.
  int srcA[4], srcB[4];
  #pragma unroll
  for (int i = 0; i < 4; ++i) {
    int off = i * 8192 + t * 16;
    int r = off >> 7, c = (off >> 4) & 7;
    int sw = (c ^ (r & 7)) << 4;
    srcA[i] = (m0 + r) * (K * 2) + sw;
    srcB[i] = (n0 + r) * (K * 2) + sw;
  }
  auto stage_half = [&](int tile, int h) {  // h: 0,1 = A halves; 2,3 = B halves
    char* db = smem + ((tile & 1) << 16) + (h << 14) + t * 16;
    const int ko = tile << 7;
    if (h < 2) {
      gload_lds16((const char*)A + srcA[2 * h] + ko, db);
      gload_lds16((const char*)A + srcA[2 * h + 1] + ko, db + 8192);
    } else {
      gload_lds16((const char*)Bw + srcB[2 * h - 4] + ko, db);
      gload_lds16((const char*)Bw + srcB[2 * h - 3] + ko, db + 8192);
    }
  };

  f32x4 acc[8][4] = {};
  const int arow = wm * 128 + lc;
  const int brow = wn * 64 + lc;

  // prologue: tile0 complete + tile1 {A0,A1,B0}; 3 newest half-tiles in flight
  stage_half(0, 0); stage_half(0, 1); stage_half(0, 2); stage_half(0, 3);
  stage_half(1, 0); stage_half(1, 1); stage_half(1, 2);
  WAITVM(6);
  BARRIER;

  for (int T = 0; T < nk; ++T) {
    const char* bufA = smem + ((T & 1) << 16);
    const char* bufB = bufA + 32768;
    short8 a0[4][2], a1[4][2], b[2][2];
    // ---- phase 0: M0 x N0 (12 ds_read) ; issue (T+1).B1 ----
    #pragma unroll
    for (int mi = 0; mi < 4; ++mi) {
      int ra = arow + mi * 16, sw = ra & 7;
      a0[mi][0] = *(const short8*)(bufA + ra * 128 + ((lg ^ sw) << 4));
      a0[mi][1] = *(const short8*)(bufA + ra * 128 + (((4 + lg) ^ sw) << 4));
    }
    #pragma unroll
    for (int ni = 0; ni < 2; ++ni) {
      int rn = brow + ni * 16, sw = rn & 7;
      b[ni][0] = *(const short8*)(bufB + rn * 128 + ((lg ^ sw) << 4));
      b[ni][1] = *(const short8*)(bufB + rn * 128 + (((4 + lg) ^ sw) << 4));
    }
    if (T + 1 < nk) stage_half(T + 1, 3);
    BARRIER; WAITLGKM0;
    __builtin_amdgcn_s_setprio(1);
    #pragma unroll
    for (int mi = 0; mi < 4; ++mi)
      #pragma unroll
      for (int ni = 0; ni < 2; ++ni) {
        acc[mi][ni] = MFMA16(a0[mi][0], b[ni][0], acc[mi][ni]);
        acc[mi][ni] = MFMA16(a0[mi][1], b[ni][1], acc[mi][ni]);
      }
    __builtin_amdgcn_s_setprio(0);
    BARRIER;
    // ---- phase 1: M1 x N0 (8 ds_read) ----
    #pragma unroll
    for (int mi = 0; mi < 4; ++mi) {
      int ra = arow + 64 + mi * 16, sw = ra & 7;
      a1[mi][0] = *(const short8*)(bufA + ra * 128 + ((lg ^ sw) << 4));
      a1[mi][1] = *(const short8*)(bufA + ra * 128 + (((4 + lg) ^ sw) << 4));
    }
    BARRIER; WAITLGKM0;
    __builtin_amdgcn_s_setprio(1);
    #pragma unroll
    for (int mi = 0; mi < 4; ++mi)
      #pragma unroll
      for (int ni = 0; ni < 2; ++ni) {
        acc[4 + mi][ni] = MFMA16(a1[mi][0], b[ni][0], acc[4 + mi][ni]);
        acc[4 + mi][ni] = MFMA16(a1[mi][1], b[ni][1], acc[4 + mi][ni]);
      }
    __builtin_amdgcn_s_setprio(0);
    BARRIER;
    // ---- phase 2: M0 x N1 (4 ds_read) ; issue (T+2).A0 (A-LDS free) ----
    #pragma unroll
    for (int ni = 0; ni < 2; ++ni) {
      int rn = brow + 32 + ni * 16, sw = rn & 7;
      b[ni][0] = *(const short8*)(bufB + rn * 128 + ((lg ^ sw) << 4));
      b[ni][1] = *(const short8*)(bufB + rn * 128 + (((4 + lg) ^ sw) << 4));
    }
    if (T + 2 < nk) stage_half(T + 2, 0);
    BARRIER; WAITLGKM0;
    __builtin_amdgcn_s_setprio(1);
    #pragma unroll
    for (int mi = 0; mi < 4; ++mi)
      #pragma unroll
      for (int ni = 0; ni < 2; ++ni) {
        acc[mi][2 + ni] = MFMA16(a0[mi][0], b[ni][0], acc[mi][2 + ni]);
        acc[mi][2 + ni] = MFMA16(a0[mi][1], b[ni][1], acc[mi][2 + ni]);
      }
    __builtin_amdgcn_s_setprio(0);
    BARRIER;
    // ---- phase 3: M1 x N1 (0 ds_read) ; issue (T+2).A1 + (T+2).B0 ----
    if (T + 2 < nk) { stage_half(T + 2, 1); stage_half(T + 2, 2); }
    BARRIER;
    __builtin_amdgcn_s_setprio(1);
    #pragma unroll
    for (int mi = 0; mi < 4; ++mi)
      #pragma unroll
      for (int ni = 0; ni < 2; ++ni) {
        acc[4 + mi][2 + ni] = MFMA16(a1[mi][0], b[ni][0], acc[4 + mi][2 + ni]);
        acc[4 + mi][2 + ni] = MFMA16(a1[mi][1], b[ni][1], acc[4 + mi][2 + ni]);
      }
    __builtin_amdgcn_s_setprio(0);
    if (T < nk - 2) { WAITVM(6); } else if (T == nk - 2) { WAITVM(0); }
    BARRIER;
  }
  __syncthreads();

  // ---- epilogue: row = m0+wm*128+p*64+mi*16+lg*4+rr, col = n0+wn*64+ni*16+lc
  const int colb = n0 + wn * 64 + lc;
  short* sl = (short*)(smem + w * 9216);  // 8 x 9216 = 72KB <= 128KB
  const int s8 = ln >> 3, c8 = ln & 7;
  const bool isV = (EPI == 0) && (n0 + wn * 64 >= 2048);
  #pragma unroll
  for (int p = 0; p < 2; ++p) {           // two 64-row passes over same region
    if (p) { WAITLGKM0; }                 // pass-0 sl reads retired before rewrite
    #pragma unroll
    for (int ni = 0; ni < 4; ++ni) {
      float bv = bias[colb + ni * 16];
      #pragma unroll
      for (int mi = 0; mi < 4; ++mi)
        #pragma unroll
        for (int rr = 0; rr < 4; ++rr) {
          int row_l = mi * 16 + lg * 4 + rr;
          int col_l = ni * 16 + lc;
          float v = acc[p * 4 + mi][ni][rr] + bv;
          if constexpr (EPI == 1) {
            float u2 = v * v;
            float mexp = v * (-2.302206744f - 0.102953795f * u2);
            v = v / (1.0f + exp2f(mexp));
          }
          if (isV) sl[col_l * 72 + row_l] = (short)f2bf(v);
          else     sl[row_l * 72 + col_l] = (short)f2bf(v);
        }
    }
    if constexpr (EPI == 0) {
      const int b_ = m0 >> 10;
      const int l0 = (m0 & 1023) + wm * 128 + p * 64;
      const int h_ = ((n0 + wn * 64) >> 6) & 15;
      const size_t bh = (size_t)(b_ * NH + h_);
      if (!isV) {
        char* dst = (char*)((n0 + wn * 64 < 1024) ? out0 : out1) +
                    (((bh << 10) + (size_t)l0) << 7);
        #pragma unroll
        for (int j = 0; j < 8; ++j) {
          short8 v8 = *(const short8*)(sl + (j * 8 + s8) * 72 + c8 * 8);
          *(short8*)(dst + j * 1024 + ln * 16) = v8;
        }
      } else {
        char* dst = (char*)out2 + bh * 131072 + (size_t)l0 * 2 + c8 * 16;
        #pragma unroll
        for (int j = 0; j < 8; ++j) {
          short8 v8 = *(const short8*)(sl + (j * 8 + s8) * 72 + c8 * 8);
          *(short8*)(dst + (size_t)(j * 8 + s8) * 2048) = v8;
        }
      }
    } else {
      char* dst = (char*)out0 + (size_t)(m0 + wm * 128 + p * 64) * ((size_t)N * 2) +
                  (size_t)(n0 + wn * 64) * 2 + c8 * 16;
      #pragma unroll
      for (int j = 0; j < 8; ++j) {
        short8 v8 = *(const short8*)(sl + (j * 8 + s8) * 72 + c8 * 8);
        *(short8*)(dst + (size_t)(j * 8 + s8) * ((size_t)N * 2)) = v8;
      }
    }
  }
}

// ---------- flash attention (r2 structure, unchanged) ----------
__global__ __launch_bounds__(512) void attn_kernel(const unsigned short* __restrict__ Q,
                                                   const unsigned short* __restrict__ Kb,
                                                   const unsigned short* __restrict__ Vt,
                                                   const unsigned* __restrict__ mp,
                                                   unsigned short* __restrict__ ctx) {
  __shared__ __align__(16) char kv[2][16384];      // [K tile 8KB | V tile 8KB] x2
  __shared__ __align__(16) short plds[8][16][72];  // per-wave P tile, padded rows
  const int t = threadIdx.x, wv = t >> 6, ln = t & 63;
  const int bid = blockIdx.x;
  const int wg = (bid & 7) * 128 + (bid >> 3);     // XCD swizzle (grid 1024)
  const int qt = wg & 7, h_ = (wg >> 3) & 15, b_ = wg >> 7;
  const int bh = b_ * NH + h_;
  const int lg = ln >> 4, lc = ln & 15;
  const int qrow0 = qt * 128 + wv * 16;

  const unsigned short* qbase = Q + ((size_t)bh * LL + qrow0) * DK;
  short8 qf0 = *(const short8*)(qbase + (size_t)lc * DK + lg * 8);
  short8 qf1 = *(const short8*)(qbase + (size_t)lc * DK + 32 + lg * 8);

  short8 onesf;
  #pragma unroll
  for (int j = 0; j < 8; ++j) onesf[j] = (short)0x3F80;  // bf16 1.0

  f32x4 o[4] = {};
  f32x4 o_l = {};  // row sums via ones-column MFMA

  const char* kg = (const char*)(Kb + (size_t)bh * LL * DK);
  const char* vg = (const char*)(Vt + (size_t)bh * DK * LL);
  const int srow = ln >> 3;
  const int gc = (ln & 7) ^ srow;
  const char* ksrc = kg + (size_t)(wv * 8 + srow) * 128 + gc * 16;
  const char* vsrc = vg + (size_t)(wv * 8 + srow) * 2048 + gc * 16;

  const unsigned* mrow = mp + ((size_t)b_ * LL + qrow0) * 32;

  gload_lds16(ksrc, kv[0] + wv * 1024);
  gload_lds16(vsrc, kv[0] + 8192 + wv * 1024);
  __syncthreads();

  int cur = 0;
  for (int kt = 0; kt < 16; ++kt) {
    if (kt < 15) {
      gload_lds16(ksrc + (size_t)(kt + 1) * 8192, kv[cur ^ 1] + wv * 1024);
      gload_lds16(vsrc + (size_t)(kt + 1) * 128, kv[cur ^ 1] + 8192 + wv * 1024);
    }
    const char* kb_ = kv[cur];
    const char* vb_ = kv[cur] + 8192;
    f32x4 s[4] = {};
    #pragma unroll
    for (int c = 0; c < 4; ++c) {
      int row = c * 16 + lc;
      short8 k0 = *(const short8*)(kb_ + row * 128 + ((lg) ^ (row & 7)) * 16);
      short8 k1 = *(const short8*)(kb_ + row * 128 + ((4 + lg) ^ (row & 7)) * 16);
      s[c] = MFMA16(qf0, k0, s[c]);
      s[c] = MFMA16(qf1, k1, s[c]);
    }
    unsigned wrd[4][2];
    #pragma unroll
    for (int r = 0; r < 4; ++r) {
      const unsigned* mr = mrow + (size_t)(lg * 4 + r) * 32 + kt * 2;
      wrd[r][0] = mr[0]; wrd[r][1] = mr[1];
    }
    #pragma unroll
    for (int c = 0; c < 4; ++c)
      #pragma unroll
      for (int r = 0; r < 4; ++r) {
        bool mk = (wrd[r][c >> 1] >> ((c & 1) * 16 + lc)) & 1;
        float p = mk ? 0.0f : exp2f(fmaf(s[c][r], 0.18033688011112f, -16.0f));
        plds[wv][lg * 4 + r][c * 16 + lc] = (short)f2bf(p);
      }
    #pragma unroll
    for (int kk = 0; kk < 2; ++kk) {
      short8 pf = *(const short8*)&plds[wv][lc][kk * 32 + lg * 8];
      o_l = MFMA16(pf, onesf, o_l);
      #pragma unroll
      for (int dt = 0; dt < 4; ++dt) {
        int row = dt * 16 + lc;
        short8 vf = *(const short8*)(vb_ + row * 128 + ((kk * 4 + lg) ^ (row & 7)) * 16);
        o[dt] = MFMA16(pf, vf, o[dt]);
      }
    }
    __syncthreads();
    cur ^= 1;
  }
  #pragma unroll
  for (int r = 0; r < 4; ++r) {
    float l = o_l[r];
    float inv = (l > 0.0f) ? 1.0f / l : 0.0f;
    size_t trow = (size_t)b_ * LL + qt * 128 + wv * 16 + lg * 4 + r;
    #pragma unroll
    for (int dt = 0; dt < 4; ++dt)
      ctx[trow * DM + h_ * 64 + dt * 16 + lc] = f2bf(o[dt][r] * inv);
  }
}

// ---------- launch ----------
extern "C" void kernel_launch(void* const* d_in, const int* in_sizes, int n_in,
                              void* d_out, int out_size, void* d_ws, size_t ws_size,
                              hipStream_t stream) {
  const float* x   = (const float*)d_in[0];
  const void*  msk = d_in[1];
  const float* Wq = (const float*)d_in[2],  *bq = (const float*)d_in[3];
  const float* Wk = (const float*)d_in[4],  *bk = (const float*)d_in[5];
  const float* Wv = (const float*)d_in[6],  *bv = (const float*)d_in[7];
  const float* Wo = (const float*)d_in[8],  *bo = (const float*)d_in[9];
  const float* l1s = (const float*)d_in[10], *l1b = (const float*)d_in[11];
  const float* l2s = (const float*)d_in[12], *l2b = (const float*)d_in[13];
  const float* W1 = (const float*)d_in[14], *b1 = (const float*)d_in[15];
  const float* W2 = (const float*)d_in[16], *b2 = (const float*)d_in[17];
  float* out = (float*)d_out;
  char* ws = (char*)d_ws;
  const size_t MB = 1u << 20;

  unsigned short* wqkv = (unsigned short*)(ws + 0 * MB);  // 6MB (Wq|Wk|Wv rows)
  unsigned short* wob = (unsigned short*)(ws + 6 * MB);   // 2MB
  unsigned short* w1b = (unsigned short*)(ws + 8 * MB);   // 8MB
  unsigned short* w2b = (unsigned short*)(ws + 16 * MB);  // 8MB
  unsigned short* xn  = (unsigned short*)(ws + 24 * MB);  // 16MB (reused as ctx)
  unsigned short* qb  = (unsigned short*)(ws + 40 * MB);  // 16MB (reused as xn2)
  unsigned short* kb  = (unsigned short*)(ws + 56 * MB);  // 16MB
  unsigned short* vtb = (unsigned short*)(ws + 72 * MB);  // 16MB
  unsigned*       mpk = (unsigned*)(ws + 88 * MB);        // 1MB
  float*          bqkv = (float*)(ws + 89 * MB);          // 12KB
  int*            flg = (int*)(ws + 89 * MB + 65536);     // 4B
  unsigned short* ctx = xn;
  unsigned short* xn2 = qb;
  unsigned short* hb  = (unsigned short*)(ws + 90 * MB);  // mchunk*4096*2

  int mchunk;
  size_t avail = (ws_size > 90 * MB) ? ws_size - 90 * MB : 0;
  if      (avail >= 64 * MB) mchunk = 8192;
  else if (avail >= 16 * MB) mchunk = 2048;
  else if (avail >= 4 * MB)  mchunk = 512;
  else                       mchunk = 256;

  // fused prep: weights -> bf16, bias concat, mask dtype detect
  prep_kernel<<<6157, 256, 0, stream>>>(Wq, Wk, Wv, Wo, W1, W2, bq, bk, bv,
                                        wqkv, wob, w1b, w2b, bqkv,
                                        (const unsigned*)msk, flg);

  // LN1 + mask pack (1024 extra blocks)
  ln_kernel<<<TT + 1024, 256, 0, stream>>>(x, l1s, l1b, xn, msk, mpk, flg, 1024);

  // fused QKV projection (M=8192, N=3072, K=1024) -- 256^2 8-phase
  gemm8<0><<<dim3(32, 12), 512, 0, stream>>>(xn, wqkv, bqkv, qb, kb, vtb,
                                             3072, DM);

  // attention (1024 blocks: 8 b * 16 h * 8 q-tiles of 128 rows)
  attn_kernel<<<1024, 512, 0, stream>>>(qb, kb, vtb, mpk, ctx);

  // Wo + residual -> d_out (fp32); N=1024 stays on 128^2 (grid 512 blocks)
  gemm5<2><<<dim3(64, 8), 256, 0, stream>>>(ctx, wob, bo, out, nullptr, nullptr,
                                            x, DM, DM);

  // LN2
  ln_kernel<<<TT, 256, 0, stream>>>(out, l2s, l2b, xn2, nullptr, nullptr, flg, 0);

  // FFN, chunked over M to bound scratch
  for (int off = 0; off < TT; off += mchunk) {
    // W1+GELU (N=4096) -- 256^2 8-phase
    gemm8<1><<<dim3(mchunk / 256, 16), 512, 0, stream>>>(
        xn2 + (size_t)off * DM, w1b, b1, hb, nullptr, nullptr, FF, DM);
    // W2 accumulate (N=1024) stays on 128^2 (grid 512 blocks)
    gemm5<3><<<dim3(mchunk / 128, 8), 256, 0, stream>>>(
        hb, w2b, b2, out + (size_t)off * DM, nullptr, nullptr, nullptr, DM, FF);
  }
}

// Round 3
// 391.563 us; speedup vs baseline: 1.0136x; 1.0136x over previous
//
#include <hip/hip_runtime.h>
#include <cstdint>
#include <cstddef>

// ---------- types ----------
typedef __attribute__((ext_vector_type(8))) short short8;     // 8 x bf16
typedef __attribute__((ext_vector_type(4))) float f32x4;
typedef __attribute__((ext_vector_type(4))) unsigned short ushort4v;

#define DEVI __device__ __forceinline__

DEVI unsigned short f2bf(float f) {  // RNE f32 -> bf16 bits
  union { float f; unsigned u; } x; x.f = f;
  unsigned r = x.u + 0x7fffu + ((x.u >> 16) & 1u);
  return (unsigned short)(r >> 16);
}

#define MFMA16(a, b, c) __builtin_amdgcn_mfma_f32_16x16x32_bf16(a, b, c, 0, 0, 0)
#define FENCE asm volatile("" ::: "memory")
#define WAITVM(n) asm volatile("s_waitcnt vmcnt(" #n ")" ::: "memory")
#define WAITLGKM0 asm volatile("s_waitcnt lgkmcnt(0)" ::: "memory")
#define BARRIER do { FENCE; __builtin_amdgcn_s_barrier(); FENCE; } while (0)

typedef __attribute__((address_space(1))) const void g_void;
typedef __attribute__((address_space(3))) void lds_void;
DEVI void gload_lds16(const void* g, void* l) {
  __builtin_amdgcn_global_load_lds((g_void*)g, (lds_void*)l, 16, 0, 0);
}

// ---------- constants ----------
static constexpr int DM = 1024;   // d_model
static constexpr int NH = 16;     // heads
static constexpr int DK = 64;     // head dim
static constexpr int FF = 4096;   // d_ff
static constexpr int BB = 8;      // batch
static constexpr int LL = 1024;   // seq
static constexpr int TT = BB * LL; // 8192 tokens

// ---------- fused prep: 6 weight cvts + QKV bias concat + mask dtype detect ----
__global__ __launch_bounds__(256) void prep_kernel(
    const float* __restrict__ Wq, const float* __restrict__ Wk,
    const float* __restrict__ Wv, const float* __restrict__ Wo,
    const float* __restrict__ W1, const float* __restrict__ W2,
    const float* __restrict__ bq, const float* __restrict__ bk,
    const float* __restrict__ bv,
    unsigned short* __restrict__ wqkv, unsigned short* __restrict__ wob,
    unsigned short* __restrict__ w1b, unsigned short* __restrict__ w2b,
    float* __restrict__ bqkv, const unsigned* __restrict__ mask,
    int* __restrict__ flag) {
  int b = blockIdx.x;
  if (b < 6144) {
    int i = b * 256 + threadIdx.x;
    const float* src; unsigned short* dst; int li;
    if (i < 131072)      { src = Wq; dst = wqkv;             li = i; }
    else if (i < 262144) { src = Wk; dst = wqkv + (1 << 20); li = i - 131072; }
    else if (i < 393216) { src = Wv; dst = wqkv + (2 << 20); li = i - 262144; }
    else if (i < 524288) { src = Wo; dst = wob;              li = i - 393216; }
    else if (i < 1048576){ src = W1; dst = w1b;              li = i - 524288; }
    else                 { src = W2; dst = w2b;              li = i - 1048576; }
    const f32x4* s4 = (const f32x4*)src;
    f32x4 a = s4[li * 2], c = s4[li * 2 + 1];
    short8 o;
    o[0] = (short)f2bf(a[0]); o[1] = (short)f2bf(a[1]);
    o[2] = (short)f2bf(a[2]); o[3] = (short)f2bf(a[3]);
    o[4] = (short)f2bf(c[0]); o[5] = (short)f2bf(c[1]);
    o[6] = (short)f2bf(c[2]); o[7] = (short)f2bf(c[3]);
    *(short8*)(dst + (size_t)li * 8) = o;
  } else if (b < 6156) {
    int i = (b - 6144) * 256 + threadIdx.x;  // 3072
    bqkv[i] = (i < 1024) ? bq[i] : (i < 2048 ? bk[i - 1024] : bv[i - 2048]);
  } else {
    unsigned a = 0;
    for (int i = threadIdx.x; i < 4096; i += 256) a |= mask[i];
    #pragma unroll
    for (int off = 32; off >= 1; off >>= 1) a |= __shfl_xor(a, off);
    __shared__ unsigned sh[4];
    if ((threadIdx.x & 63) == 0) sh[threadIdx.x >> 6] = a;
    __syncthreads();
    if (threadIdx.x == 0) {
      unsigned o = sh[0] | sh[1] | sh[2] | sh[3];
      flag[0] = (o & 0xFEFEFEFEu) ? 2 : ((o & 0xFFFFFF00u) ? 1 : 0);
    }
  }
}

// ---------- LayerNorm (fp32 in, bf16 out) + optional mask-pack blocks ----------
__global__ __launch_bounds__(256) void ln_kernel(const float* __restrict__ x,
                                                 const float* __restrict__ sc,
                                                 const float* __restrict__ bi,
                                                 unsigned short* __restrict__ out,
                                                 const void* __restrict__ mask,
                                                 unsigned* __restrict__ mp,
                                                 const int* __restrict__ flag,
                                                 int npack) {
  int row = blockIdx.x;
  int t = threadIdx.x;
  if (row >= TT) {
    int w = (row - TT) * 256 + t;   // word over B*L*(L/32) = 262144
    int cls = flag[0];
    unsigned bits = 0u;
    if (cls == 1) {
      const unsigned char* mb = (const unsigned char*)mask + (size_t)w * 32;
      #pragma unroll 8
      for (int i = 0; i < 32; ++i) bits |= (mb[i] ? 1u : 0u) << i;
    } else {
      const unsigned* mi = (const unsigned*)mask + (size_t)w * 32;
      #pragma unroll 8
      for (int i = 0; i < 32; ++i) bits |= (mi[i] ? 1u : 0u) << i;
    }
    mp[w] = bits;
    return;
  }
  const f32x4* xr = (const f32x4*)(x + (size_t)row * DM);
  f32x4 v = xr[t];
  float s = v[0] + v[1] + v[2] + v[3];
  float q = v[0]*v[0] + v[1]*v[1] + v[2]*v[2] + v[3]*v[3];
  #pragma unroll
  for (int off = 32; off >= 1; off >>= 1) { s += __shfl_xor(s, off); q += __shfl_xor(q, off); }
  __shared__ float red[8];
  int wv = t >> 6;
  if ((t & 63) == 0) { red[wv] = s; red[4 + wv] = q; }
  __syncthreads();
  s = red[0] + red[1] + red[2] + red[3];
  q = red[4] + red[5] + red[6] + red[7];
  float mu = s * (1.0f / DM);
  float var = q * (1.0f / DM) - mu * mu;
  float rs = rsqrtf(var + 1e-5f);
  f32x4 sv = ((const f32x4*)sc)[t], bv = ((const f32x4*)bi)[t];
  ushort4v o;
  #pragma unroll
  for (int j = 0; j < 4; ++j) o[j] = f2bf((v[j] - mu) * rs * sv[j] + bv[j]);
  *(ushort4v*)(out + (size_t)row * DM + t * 4) = o;
}

// ---------- GEMM v9: 128x128, dbuf pipelined, 2 blocks/CU (kept for N=1024) ----
template <int EPI>
__global__ __launch_bounds__(256, 2)
void gemm5(const unsigned short* __restrict__ A, const unsigned short* __restrict__ Bw,
           const float* __restrict__ bias, void* __restrict__ out0,
           void* __restrict__ out1, void* __restrict__ out2,
           const float* __restrict__ res, int N, int K) {
  __shared__ __align__(16) char smem[65536];  // 2 x 32KB
  const int t = threadIdx.x;
  const int w = t >> 6, ln = t & 63;
  const int wm = w >> 1, wn = w & 1;
  const int lg = ln >> 4, lc = ln & 15;
  const int m0 = blockIdx.x * 128, n0 = blockIdx.y * 128;
  const size_t rb = (size_t)K * 2;
  const int nk = K >> 6;

  const char* srcp[8];
  #pragma unroll
  for (int i = 0; i < 8; ++i) {
    int off = i * 4096 + t * 16;
    if (off < 16384) {
      int r = off >> 7, c = (off >> 4) & 7;
      srcp[i] = (const char*)A + (size_t)(m0 + r) * rb + ((c ^ (r & 7)) << 4);
    } else {
      int ob = off - 16384;
      int r = ob >> 7, c = (ob >> 4) & 7;
      srcp[i] = (const char*)Bw + (size_t)(n0 + r) * rb + ((c ^ (r & 7)) << 4);
    }
  }
  auto stage8 = [&](int tile) {
    char* db = smem + ((tile & 1) << 15) + t * 16;
    const size_t ko = (size_t)tile << 7;
    #pragma unroll
    for (int i = 0; i < 8; ++i) gload_lds16(srcp[i] + ko, db + i * 4096);
  };

  int aoff[4][2], boff[4][2];
  #pragma unroll
  for (int x_ = 0; x_ < 4; ++x_)
    #pragma unroll
    for (int kk = 0; kk < 2; ++kk) {
      int ra = wm * 64 + x_ * 16 + lc;
      aoff[x_][kk] = ra * 128 + (((kk * 4 + lg) ^ (ra & 7)) << 4);
      int rn = wn * 64 + x_ * 16 + lc;
      boff[x_][kk] = 16384 + rn * 128 + (((kk * 4 + lg) ^ (rn & 7)) << 4);
    }

  f32x4 acc[4][4] = {};

  stage8(0);
  for (int T = 0; T < nk; ++T) {
    if (T + 1 < nk) stage8(T + 1);
    if (T == nk - 1) { WAITVM(0); } else { WAITVM(8); }  // tile T landed
    BARRIER;
    const char* buf = smem + ((T & 1) << 15);
    short8 afr[4][2], bfr[4][2];
    #pragma unroll
    for (int ni = 0; ni < 4; ++ni) {
      bfr[ni][0] = *(const short8*)(buf + boff[ni][0]);
      bfr[ni][1] = *(const short8*)(buf + boff[ni][1]);
    }
    #pragma unroll
    for (int mi = 0; mi < 4; ++mi) {
      afr[mi][0] = *(const short8*)(buf + aoff[mi][0]);
      afr[mi][1] = *(const short8*)(buf + aoff[mi][1]);
    }
    __builtin_amdgcn_s_setprio(1);
    #pragma unroll
    for (int mi = 0; mi < 4; ++mi)
      #pragma unroll
      for (int ni = 0; ni < 4; ++ni) {
        acc[mi][ni] = MFMA16(afr[mi][0], bfr[ni][0], acc[mi][ni]);
        acc[mi][ni] = MFMA16(afr[mi][1], bfr[ni][1], acc[mi][ni]);
      }
    __builtin_amdgcn_s_setprio(0);
    WAITLGKM0;
    BARRIER;
  }
  __syncthreads();

  const int colb = n0 + wn * 64 + lc;
  const int rowb = m0 + wm * 64 + lg * 4;
  if constexpr (EPI >= 2) {
    #pragma unroll
    for (int ni = 0; ni < 4; ++ni) {
      int col = colb + ni * 16;
      float bv = bias[col];
      #pragma unroll
      for (int mi = 0; mi < 4; ++mi)
        #pragma unroll
        for (int rr = 0; rr < 4; ++rr) {
          int row = rowb + mi * 16 + rr;
          float v = acc[mi][ni][rr] + bv;
          if constexpr (EPI == 2)
            ((float*)out0)[(size_t)row * N + col] = res[(size_t)row * N + col] + v;
          else
            ((float*)out0)[(size_t)row * N + col] += v;
        }
    }
  } else {
    short* sl = (short*)(smem + w * 9216);
    const bool isV = (EPI == 0) && (n0 + wn * 64 >= 2048);
    #pragma unroll
    for (int ni = 0; ni < 4; ++ni) {
      float bv = bias[colb + ni * 16];
      #pragma unroll
      for (int mi = 0; mi < 4; ++mi)
        #pragma unroll
        for (int rr = 0; rr < 4; ++rr) {
          int row_l = mi * 16 + lg * 4 + rr;
          int col_l = ni * 16 + lc;
          float v = acc[mi][ni][rr] + bv;
          if constexpr (EPI == 1) {
            float u2 = v * v;
            float mexp = v * (-2.302206744f - 0.102953795f * u2);
            v = v / (1.0f + exp2f(mexp));
          }
          if (isV) sl[col_l * 72 + row_l] = (short)f2bf(v);
          else     sl[row_l * 72 + col_l] = (short)f2bf(v);
        }
    }
    const int s8 = ln >> 3, c8 = ln & 7;
    if constexpr (EPI == 0) {
      const int b_ = m0 >> 10;
      const int l0 = (m0 & 1023) + wm * 64;
      const int h_ = ((n0 + wn * 64) >> 6) & 15;
      const size_t bh = (size_t)(b_ * NH + h_);
      if (n0 + wn * 64 < 2048) {
        char* dst = (char*)((n0 + wn * 64 < 1024) ? out0 : out1) + (((bh << 10) + l0) << 7);
        #pragma unroll
        for (int j = 0; j < 8; ++j) {
          short8 v8 = *(const short8*)(sl + (j * 8 + s8) * 72 + c8 * 8);
          *(short8*)(dst + j * 1024 + ln * 16) = v8;
        }
      } else {
        char* dst = (char*)out2 + bh * 131072 + l0 * 2 + c8 * 16;
        #pragma unroll
        for (int j = 0; j < 8; ++j) {
          short8 v8 = *(const short8*)(sl + (j * 8 + s8) * 72 + c8 * 8);
          *(short8*)(dst + (size_t)(j * 8 + s8) * 2048) = v8;
        }
      }
    } else {
      char* dst = (char*)out0 + (size_t)(m0 + wm * 64) * ((size_t)N * 2) +
                  (size_t)(n0 + wn * 64) * 2 + c8 * 16;
      #pragma unroll
      for (int j = 0; j < 8; ++j) {
        short8 v8 = *(const short8*)(sl + (j * 8 + s8) * 72 + c8 * 8);
        *(short8*)(dst + (size_t)(j * 8 + s8) * ((size_t)N * 2)) = v8;
      }
    }
  }
}

// ---------- GEMM v10c: 256x256 8-phase + compact per-XCD 2D patches ---------
// Round-2 diagnosis: the 1-D XCD swizzle gave each XCD all 32 M-tiles x 2
// N-tiles -> every XCD streamed the whole 16MB A through its 4MB L2:
// FETCH = 8x16MB + B = 135MB for BOTH QKV and W1 (exact match), pinning the
// kernel at ~2TB/s L2-miss traffic (~4000 stall cyc/K-tile).
// Fix: 4(M) x 2(N) patch grid; XCD owns an 8-Mtile band (4MB A = L2-resident
// for the whole patch) x gy/2 N-tiles streamed once. Expected FETCH:
// A x2 + B x4 ~= 55-65MB.
template <int EPI>
__global__ __launch_bounds__(512, 1)
void gemm8(const unsigned short* __restrict__ A, const unsigned short* __restrict__ Bw,
           const float* __restrict__ bias, void* __restrict__ out0,
           void* __restrict__ out1, void* __restrict__ out2, int N, int K) {
  __shared__ __align__(16) char smem[131072];  // 2 x (A 32KB | B 32KB)
  const int t = threadIdx.x;
  const int w = t >> 6, ln = t & 63;
  const int wm = w >> 2, wn = w & 3;           // 2M x 4N waves
  const int lg = ln >> 4, lc = ln & 15;

  // compact per-XCD patches: requires gx%4==0, gy%2==0, nwg%8==0 (our grids:
  // 32x12, 32x16). xcd = orig&7 (dispatch round-robins XCDs); within-XCD
  // temporal order = idx ascending = M-fast scan, so the A-band is reused
  // across all N-columns of the patch.
  {
    const int gx = gridDim.x, gy = gridDim.y;
    int orig = blockIdx.y * gx + blockIdx.x;
    int xcd = orig & 7, idx = orig >> 3;
    const int pmt = gx >> 2, pnt = gy >> 1;    // patch dims in tiles
    const int mt = (xcd >> 1) * pmt + (idx % pmt);
    const int nt = (xcd & 1) * pnt + (idx / pmt);
    // stash in m0/n0 below
    __builtin_amdgcn_sched_barrier(0);
    (void)mt; (void)nt;
    // fallthrough via locals:
    #define M0_ (mt * 256)
    #define N0_ (nt * 256)
    const int m0 = M0_, n0 = N0_;
    #undef M0_
    #undef N0_

    const int nk = K >> 6;

    // staging: 8 slots of 8KB per tile ([A0 A1 | B0 B1] halves);
    // LDS dest linear, global source pre-XOR-swizzled by row.
    int srcA[4], srcB[4];
    #pragma unroll
    for (int i = 0; i < 4; ++i) {
      int off = i * 8192 + t * 16;
      int r = off >> 7, c = (off >> 4) & 7;
      int sw = (c ^ (r & 7)) << 4;
      srcA[i] = (m0 + r) * (K * 2) + sw;
      srcB[i] = (n0 + r) * (K * 2) + sw;
    }
    auto stage_half = [&](int tile, int h) {  // h: 0,1 = A halves; 2,3 = B
      char* db = smem + ((tile & 1) << 16) + (h << 14) + t * 16;
      const int ko = tile << 7;
      if (h < 2) {
        gload_lds16((const char*)A + srcA[2 * h] + ko, db);
        gload_lds16((const char*)A + srcA[2 * h + 1] + ko, db + 8192);
      } else {
        gload_lds16((const char*)Bw + srcB[2 * h - 4] + ko, db);
        gload_lds16((const char*)Bw + srcB[2 * h - 3] + ko, db + 8192);
      }
    };

    f32x4 acc[8][4] = {};
    const int arow = wm * 128 + lc;
    const int brow = wn * 64 + lc;

    // prologue: tile0 complete + tile1 {A0,A1,B0}
    stage_half(0, 0); stage_half(0, 1); stage_half(0, 2); stage_half(0, 3);
    stage_half(1, 0); stage_half(1, 1); stage_half(1, 2);
    WAITVM(6);
    BARRIER;

    for (int T = 0; T < nk; ++T) {
      const char* bufA = smem + ((T & 1) << 16);
      const char* bufB = bufA + 32768;
      short8 a0[4][2], a1[4][2], b[2][2];
      // ---- phase 0: M0 x N0 (12 ds_read) ; issue (T+1).B1 ----
      #pragma unroll
      for (int mi = 0; mi < 4; ++mi) {
        int ra = arow + mi * 16, sw = ra & 7;
        a0[mi][0] = *(const short8*)(bufA + ra * 128 + ((lg ^ sw) << 4));
        a0[mi][1] = *(const short8*)(bufA + ra * 128 + (((4 + lg) ^ sw) << 4));
      }
      #pragma unroll
      for (int ni = 0; ni < 2; ++ni) {
        int rn = brow + ni * 16, sw = rn & 7;
        b[ni][0] = *(const short8*)(bufB + rn * 128 + ((lg ^ sw) << 4));
        b[ni][1] = *(const short8*)(bufB + rn * 128 + (((4 + lg) ^ sw) << 4));
      }
      if (T + 1 < nk) stage_half(T + 1, 3);
      BARRIER; WAITLGKM0;
      __builtin_amdgcn_s_setprio(1);
      #pragma unroll
      for (int mi = 0; mi < 4; ++mi)
        #pragma unroll
        for (int ni = 0; ni < 2; ++ni) {
          acc[mi][ni] = MFMA16(a0[mi][0], b[ni][0], acc[mi][ni]);
          acc[mi][ni] = MFMA16(a0[mi][1], b[ni][1], acc[mi][ni]);
        }
      __builtin_amdgcn_s_setprio(0);
      BARRIER;
      // ---- phase 1: M1 x N0 (8 ds_read) ----
      #pragma unroll
      for (int mi = 0; mi < 4; ++mi) {
        int ra = arow + 64 + mi * 16, sw = ra & 7;
        a1[mi][0] = *(const short8*)(bufA + ra * 128 + ((lg ^ sw) << 4));
        a1[mi][1] = *(const short8*)(bufA + ra * 128 + (((4 + lg) ^ sw) << 4));
      }
      BARRIER; WAITLGKM0;
      __builtin_amdgcn_s_setprio(1);
      #pragma unroll
      for (int mi = 0; mi < 4; ++mi)
        #pragma unroll
        for (int ni = 0; ni < 2; ++ni) {
          acc[4 + mi][ni] = MFMA16(a1[mi][0], b[ni][0], acc[4 + mi][ni]);
          acc[4 + mi][ni] = MFMA16(a1[mi][1], b[ni][1], acc[4 + mi][ni]);
        }
      __builtin_amdgcn_s_setprio(0);
      BARRIER;
      // ---- phase 2: M0 x N1 (4 ds_read) ; issue (T+2).A0 ----
      #pragma unroll
      for (int ni = 0; ni < 2; ++ni) {
        int rn = brow + 32 + ni * 16, sw = rn & 7;
        b[ni][0] = *(const short8*)(bufB + rn * 128 + ((lg ^ sw) << 4));
        b[ni][1] = *(const short8*)(bufB + rn * 128 + (((4 + lg) ^ sw) << 4));
      }
      if (T + 2 < nk) stage_half(T + 2, 0);
      BARRIER; WAITLGKM0;
      __builtin_amdgcn_s_setprio(1);
      #pragma unroll
      for (int mi = 0; mi < 4; ++mi)
        #pragma unroll
        for (int ni = 0; ni < 2; ++ni) {
          acc[mi][2 + ni] = MFMA16(a0[mi][0], b[ni][0], acc[mi][2 + ni]);
          acc[mi][2 + ni] = MFMA16(a0[mi][1], b[ni][1], acc[mi][2 + ni]);
        }
      __builtin_amdgcn_s_setprio(0);
      BARRIER;
      // ---- phase 3: M1 x N1 (0 ds_read) ; issue (T+2).A1 + (T+2).B0 ----
      if (T + 2 < nk) { stage_half(T + 2, 1); stage_half(T + 2, 2); }
      BARRIER;
      __builtin_amdgcn_s_setprio(1);
      #pragma unroll
      for (int mi = 0; mi < 4; ++mi)
        #pragma unroll
        for (int ni = 0; ni < 2; ++ni) {
          acc[4 + mi][2 + ni] = MFMA16(a1[mi][0], b[ni][0], acc[4 + mi][2 + ni]);
          acc[4 + mi][2 + ni] = MFMA16(a1[mi][1], b[ni][1], acc[4 + mi][2 + ni]);
        }
      __builtin_amdgcn_s_setprio(0);
      if (T < nk - 2) { WAITVM(6); } else if (T == nk - 2) { WAITVM(0); }
      BARRIER;
    }
    __syncthreads();

    // ---- epilogue: row = m0+wm*128+p*64+mi*16+lg*4+rr, col = n0+wn*64+ni*16+lc
    const int colb = n0 + wn * 64 + lc;
    short* sl = (short*)(smem + w * 9216);  // 8 x 9216 = 72KB <= 128KB
    const int s8 = ln >> 3, c8 = ln & 7;
    const bool isV = (EPI == 0) && (n0 + wn * 64 >= 2048);
    #pragma unroll
    for (int p = 0; p < 2; ++p) {           // two 64-row passes
      if (p) { WAITLGKM0; }
      #pragma unroll
      for (int ni = 0; ni < 4; ++ni) {
        float bv = bias[colb + ni * 16];
        #pragma unroll
        for (int mi = 0; mi < 4; ++mi)
          #pragma unroll
          for (int rr = 0; rr < 4; ++rr) {
            int row_l = mi * 16 + lg * 4 + rr;
            int col_l = ni * 16 + lc;
            float v = acc[p * 4 + mi][ni][rr] + bv;
            if constexpr (EPI == 1) {
              float u2 = v * v;
              float mexp = v * (-2.302206744f - 0.102953795f * u2);
              v = v / (1.0f + exp2f(mexp));
            }
            if (isV) sl[col_l * 72 + row_l] = (short)f2bf(v);
            else     sl[row_l * 72 + col_l] = (short)f2bf(v);
          }
      }
      if constexpr (EPI == 0) {
        const int b_ = m0 >> 10;
        const int l0 = (m0 & 1023) + wm * 128 + p * 64;
        const int h_ = ((n0 + wn * 64) >> 6) & 15;
        const size_t bh = (size_t)(b_ * NH + h_);
        if (!isV) {
          char* dst = (char*)((n0 + wn * 64 < 1024) ? out0 : out1) +
                      (((bh << 10) + (size_t)l0) << 7);
          #pragma unroll
          for (int j = 0; j < 8; ++j) {
            short8 v8 = *(const short8*)(sl + (j * 8 + s8) * 72 + c8 * 8);
            *(short8*)(dst + j * 1024 + ln * 16) = v8;
          }
        } else {
          char* dst = (char*)out2 + bh * 131072 + (size_t)l0 * 2 + c8 * 16;
          #pragma unroll
          for (int j = 0; j < 8; ++j) {
            short8 v8 = *(const short8*)(sl + (j * 8 + s8) * 72 + c8 * 8);
            *(short8*)(dst + (size_t)(j * 8 + s8) * 2048) = v8;
          }
        }
      } else {
        char* dst = (char*)out0 + (size_t)(m0 + wm * 128 + p * 64) * ((size_t)N * 2) +
                    (size_t)(n0 + wn * 64) * 2 + c8 * 16;
        #pragma unroll
        for (int j = 0; j < 8; ++j) {
          short8 v8 = *(const short8*)(sl + (j * 8 + s8) * 72 + c8 * 8);
          *(short8*)(dst + (size_t)(j * 8 + s8) * ((size_t)N * 2)) = v8;
        }
      }
    }
  }
}

// ---------- flash attention (r2 structure, unchanged) ----------
__global__ __launch_bounds__(512) void attn_kernel(const unsigned short* __restrict__ Q,
                                                   const unsigned short* __restrict__ Kb,
                                                   const unsigned short* __restrict__ Vt,
                                                   const unsigned* __restrict__ mp,
                                                   unsigned short* __restrict__ ctx) {
  __shared__ __align__(16) char kv[2][16384];      // [K tile 8KB | V tile 8KB] x2
  __shared__ __align__(16) short plds[8][16][72];  // per-wave P tile, padded rows
  const int t = threadIdx.x, wv = t >> 6, ln = t & 63;
  const int bid = blockIdx.x;
  const int wg = (bid & 7) * 128 + (bid >> 3);     // XCD swizzle (grid 1024)
  const int qt = wg & 7, h_ = (wg >> 3) & 15, b_ = wg >> 7;
  const int bh = b_ * NH + h_;
  const int lg = ln >> 4, lc = ln & 15;
  const int qrow0 = qt * 128 + wv * 16;

  const unsigned short* qbase = Q + ((size_t)bh * LL + qrow0) * DK;
  short8 qf0 = *(const short8*)(qbase + (size_t)lc * DK + lg * 8);
  short8 qf1 = *(const short8*)(qbase + (size_t)lc * DK + 32 + lg * 8);

  short8 onesf;
  #pragma unroll
  for (int j = 0; j < 8; ++j) onesf[j] = (short)0x3F80;  // bf16 1.0

  f32x4 o[4] = {};
  f32x4 o_l = {};  // row sums via ones-column MFMA

  const char* kg = (const char*)(Kb + (size_t)bh * LL * DK);
  const char* vg = (const char*)(Vt + (size_t)bh * DK * LL);
  const int srow = ln >> 3;
  const int gc = (ln & 7) ^ srow;
  const char* ksrc = kg + (size_t)(wv * 8 + srow) * 128 + gc * 16;
  const char* vsrc = vg + (size_t)(wv * 8 + srow) * 2048 + gc * 16;

  const unsigned* mrow = mp + ((size_t)b_ * LL + qrow0) * 32;

  gload_lds16(ksrc, kv[0] + wv * 1024);
  gload_lds16(vsrc, kv[0] + 8192 + wv * 1024);
  __syncthreads();

  int cur = 0;
  for (int kt = 0; kt < 16; ++kt) {
    if (kt < 15) {
      gload_lds16(ksrc + (size_t)(kt + 1) * 8192, kv[cur ^ 1] + wv * 1024);
      gload_lds16(vsrc + (size_t)(kt + 1) * 128, kv[cur ^ 1] + 8192 + wv * 1024);
    }
    const char* kb_ = kv[cur];
    const char* vb_ = kv[cur] + 8192;
    f32x4 s[4] = {};
    #pragma unroll
    for (int c = 0; c < 4; ++c) {
      int row = c * 16 + lc;
      short8 k0 = *(const short8*)(kb_ + row * 128 + ((lg) ^ (row & 7)) * 16);
      short8 k1 = *(const short8*)(kb_ + row * 128 + ((4 + lg) ^ (row & 7)) * 16);
      s[c] = MFMA16(qf0, k0, s[c]);
      s[c] = MFMA16(qf1, k1, s[c]);
    }
    unsigned wrd[4][2];
    #pragma unroll
    for (int r = 0; r < 4; ++r) {
      const unsigned* mr = mrow + (size_t)(lg * 4 + r) * 32 + kt * 2;
      wrd[r][0] = mr[0]; wrd[r][1] = mr[1];
    }
    #pragma unroll
    for (int c = 0; c < 4; ++c)
      #pragma unroll
      for (int r = 0; r < 4; ++r) {
        bool mk = (wrd[r][c >> 1] >> ((c & 1) * 16 + lc)) & 1;
        float p = mk ? 0.0f : exp2f(fmaf(s[c][r], 0.18033688011112f, -16.0f));
        plds[wv][lg * 4 + r][c * 16 + lc] = (short)f2bf(p);
      }
    #pragma unroll
    for (int kk = 0; kk < 2; ++kk) {
      short8 pf = *(const short8*)&plds[wv][lc][kk * 32 + lg * 8];
      o_l = MFMA16(pf, onesf, o_l);
      #pragma unroll
      for (int dt = 0; dt < 4; ++dt) {
        int row = dt * 16 + lc;
        short8 vf = *(const short8*)(vb_ + row * 128 + ((kk * 4 + lg) ^ (row & 7)) * 16);
        o[dt] = MFMA16(pf, vf, o[dt]);
      }
    }
    __syncthreads();
    cur ^= 1;
  }
  #pragma unroll
  for (int r = 0; r < 4; ++r) {
    float l = o_l[r];
    float inv = (l > 0.0f) ? 1.0f / l : 0.0f;
    size_t trow = (size_t)b_ * LL + qt * 128 + wv * 16 + lg * 4 + r;
    #pragma unroll
    for (int dt = 0; dt < 4; ++dt)
      ctx[trow * DM + h_ * 64 + dt * 16 + lc] = f2bf(o[dt][r] * inv);
  }
}

// ---------- launch ----------
extern "C" void kernel_launch(void* const* d_in, const int* in_sizes, int n_in,
                              void* d_out, int out_size, void* d_ws, size_t ws_size,
                              hipStream_t stream) {
  const float* x   = (const float*)d_in[0];
  const void*  msk = d_in[1];
  const float* Wq = (const float*)d_in[2],  *bq = (const float*)d_in[3];
  const float* Wk = (const float*)d_in[4],  *bk = (const float*)d_in[5];
  const float* Wv = (const float*)d_in[6],  *bv = (const float*)d_in[7];
  const float* Wo = (const float*)d_in[8],  *bo = (const float*)d_in[9];
  const float* l1s = (const float*)d_in[10], *l1b = (const float*)d_in[11];
  const float* l2s = (const float*)d_in[12], *l2b = (const float*)d_in[13];
  const float* W1 = (const float*)d_in[14], *b1 = (const float*)d_in[15];
  const float* W2 = (const float*)d_in[16], *b2 = (const float*)d_in[17];
  float* out = (float*)d_out;
  char* ws = (char*)d_ws;
  const size_t MB = 1u << 20;

  unsigned short* wqkv = (unsigned short*)(ws + 0 * MB);  // 6MB (Wq|Wk|Wv rows)
  unsigned short* wob = (unsigned short*)(ws + 6 * MB);   // 2MB
  unsigned short* w1b = (unsigned short*)(ws + 8 * MB);   // 8MB
  unsigned short* w2b = (unsigned short*)(ws + 16 * MB);  // 8MB
  unsigned short* xn  = (unsigned short*)(ws + 24 * MB);  // 16MB (reused as ctx)
  unsigned short* qb  = (unsigned short*)(ws + 40 * MB);  // 16MB (reused as xn2)
  unsigned short* kb  = (unsigned short*)(ws + 56 * MB);  // 16MB
  unsigned short* vtb = (unsigned short*)(ws + 72 * MB);  // 16MB
  unsigned*       mpk = (unsigned*)(ws + 88 * MB);        // 1MB
  float*          bqkv = (float*)(ws + 89 * MB);          // 12KB
  int*            flg = (int*)(ws + 89 * MB + 65536);     // 4B
  unsigned short* ctx = xn;
  unsigned short* xn2 = qb;
  unsigned short* hb  = (unsigned short*)(ws + 90 * MB);  // mchunk*4096*2

  int mchunk;
  size_t avail = (ws_size > 90 * MB) ? ws_size - 90 * MB : 0;
  if      (avail >= 64 * MB) mchunk = 8192;
  else if (avail >= 16 * MB) mchunk = 2048;
  else if (avail >= 4 * MB)  mchunk = 512;
  else                       mchunk = 256;

  // fused prep: weights -> bf16, bias concat, mask dtype detect
  prep_kernel<<<6157, 256, 0, stream>>>(Wq, Wk, Wv, Wo, W1, W2, bq, bk, bv,
                                        wqkv, wob, w1b, w2b, bqkv,
                                        (const unsigned*)msk, flg);

  // LN1 + mask pack (1024 extra blocks)
  ln_kernel<<<TT + 1024, 256, 0, stream>>>(x, l1s, l1b, xn, msk, mpk, flg, 1024);

  // fused QKV projection (M=8192, N=3072, K=1024) -- 256^2 8-phase
  gemm8<0><<<dim3(32, 12), 512, 0, stream>>>(xn, wqkv, bqkv, qb, kb, vtb,
                                             3072, DM);

  // attention (1024 blocks: 8 b * 16 h * 8 q-tiles of 128 rows)
  attn_kernel<<<1024, 512, 0, stream>>>(qb, kb, vtb, mpk, ctx);

  // Wo + residual -> d_out (fp32); N=1024 stays on 128^2 (grid 512 blocks)
  gemm5<2><<<dim3(64, 8), 256, 0, stream>>>(ctx, wob, bo, out, nullptr, nullptr,
                                            x, DM, DM);

  // LN2
  ln_kernel<<<TT, 256, 0, stream>>>(out, l2s, l2b, xn2, nullptr, nullptr, flg, 0);

  // FFN, chunked over M to bound scratch
  for (int off = 0; off < TT; off += mchunk) {
    // W1+GELU (N=4096) -- 256^2 8-phase
    gemm8<1><<<dim3(mchunk / 256, 16), 512, 0, stream>>>(
        xn2 + (size_t)off * DM, w1b, b1, hb, nullptr, nullptr, FF, DM);
    // W2 accumulate (N=1024) stays on 128^2 (grid 512 blocks)
    gemm5<3><<<dim3(mchunk / 128, 8), 256, 0, stream>>>(
        hb, w2b, b2, out + (size_t)off * DM, nullptr, nullptr, nullptr, DM, FF);
  }
}

// Round 4
// 391.537 us; speedup vs baseline: 1.0136x; 1.0001x over previous
//
#include <hip/hip_runtime.h>
#include <cstdint>
#include <cstddef>

// ---------- types ----------
typedef __attribute__((ext_vector_type(8))) short short8;     // 8 x bf16
typedef __attribute__((ext_vector_type(4))) float f32x4;
typedef __attribute__((ext_vector_type(4))) unsigned short ushort4v;

#define DEVI __device__ __forceinline__

DEVI unsigned short f2bf(float f) {  // RNE f32 -> bf16 bits
  union { float f; unsigned u; } x; x.f = f;
  unsigned r = x.u + 0x7fffu + ((x.u >> 16) & 1u);
  return (unsigned short)(r >> 16);
}

#define MFMA16(a, b, c) __builtin_amdgcn_mfma_f32_16x16x32_bf16(a, b, c, 0, 0, 0)
#define FENCE asm volatile("" ::: "memory")
#define WAITVM(n) asm volatile("s_waitcnt vmcnt(" #n ")" ::: "memory")
#define WAITLGKM0 asm volatile("s_waitcnt lgkmcnt(0)" ::: "memory")
#define BARRIER do { FENCE; __builtin_amdgcn_s_barrier(); FENCE; } while (0)

typedef __attribute__((address_space(1))) const void g_void;
typedef __attribute__((address_space(3))) void lds_void;
DEVI void gload_lds16(const void* g, void* l) {
  __builtin_amdgcn_global_load_lds((g_void*)g, (lds_void*)l, 16, 0, 0);
}

// ---------- constants ----------
static constexpr int DM = 1024;   // d_model
static constexpr int NH = 16;     // heads
static constexpr int DK = 64;     // head dim
static constexpr int FF = 4096;   // d_ff
static constexpr int BB = 8;      // batch
static constexpr int LL = 1024;   // seq
static constexpr int TT = BB * LL; // 8192 tokens

// ---------- fused prep: 6 weight cvts + QKV bias concat + mask dtype detect ----
__global__ __launch_bounds__(256) void prep_kernel(
    const float* __restrict__ Wq, const float* __restrict__ Wk,
    const float* __restrict__ Wv, const float* __restrict__ Wo,
    const float* __restrict__ W1, const float* __restrict__ W2,
    const float* __restrict__ bq, const float* __restrict__ bk,
    const float* __restrict__ bv,
    unsigned short* __restrict__ wqkv, unsigned short* __restrict__ wob,
    unsigned short* __restrict__ w1b, unsigned short* __restrict__ w2b,
    float* __restrict__ bqkv, const unsigned* __restrict__ mask,
    int* __restrict__ flag) {
  int b = blockIdx.x;
  if (b < 6144) {
    int i = b * 256 + threadIdx.x;
    const float* src; unsigned short* dst; int li;
    if (i < 131072)      { src = Wq; dst = wqkv;             li = i; }
    else if (i < 262144) { src = Wk; dst = wqkv + (1 << 20); li = i - 131072; }
    else if (i < 393216) { src = Wv; dst = wqkv + (2 << 20); li = i - 262144; }
    else if (i < 524288) { src = Wo; dst = wob;              li = i - 393216; }
    else if (i < 1048576){ src = W1; dst = w1b;              li = i - 524288; }
    else                 { src = W2; dst = w2b;              li = i - 1048576; }
    const f32x4* s4 = (const f32x4*)src;
    f32x4 a = s4[li * 2], c = s4[li * 2 + 1];
    short8 o;
    o[0] = (short)f2bf(a[0]); o[1] = (short)f2bf(a[1]);
    o[2] = (short)f2bf(a[2]); o[3] = (short)f2bf(a[3]);
    o[4] = (short)f2bf(c[0]); o[5] = (short)f2bf(c[1]);
    o[6] = (short)f2bf(c[2]); o[7] = (short)f2bf(c[3]);
    *(short8*)(dst + (size_t)li * 8) = o;
  } else if (b < 6156) {
    int i = (b - 6144) * 256 + threadIdx.x;  // 3072
    bqkv[i] = (i < 1024) ? bq[i] : (i < 2048 ? bk[i - 1024] : bv[i - 2048]);
  } else {
    unsigned a = 0;
    for (int i = threadIdx.x; i < 4096; i += 256) a |= mask[i];
    #pragma unroll
    for (int off = 32; off >= 1; off >>= 1) a |= __shfl_xor(a, off);
    __shared__ unsigned sh[4];
    if ((threadIdx.x & 63) == 0) sh[threadIdx.x >> 6] = a;
    __syncthreads();
    if (threadIdx.x == 0) {
      unsigned o = sh[0] | sh[1] | sh[2] | sh[3];
      flag[0] = (o & 0xFEFEFEFEu) ? 2 : ((o & 0xFFFFFF00u) ? 1 : 0);
    }
  }
}

// ---------- LayerNorm (fp32 in, bf16 out) + optional mask-pack blocks ----------
__global__ __launch_bounds__(256) void ln_kernel(const float* __restrict__ x,
                                                 const float* __restrict__ sc,
                                                 const float* __restrict__ bi,
                                                 unsigned short* __restrict__ out,
                                                 const void* __restrict__ mask,
                                                 unsigned* __restrict__ mp,
                                                 const int* __restrict__ flag,
                                                 int npack) {
  int row = blockIdx.x;
  int t = threadIdx.x;
  if (row >= TT) {
    int w = (row - TT) * 256 + t;   // word over B*L*(L/32) = 262144
    int cls = flag[0];
    unsigned bits = 0u;
    if (cls == 1) {
      const unsigned char* mb = (const unsigned char*)mask + (size_t)w * 32;
      #pragma unroll 8
      for (int i = 0; i < 32; ++i) bits |= (mb[i] ? 1u : 0u) << i;
    } else {
      const unsigned* mi = (const unsigned*)mask + (size_t)w * 32;
      #pragma unroll 8
      for (int i = 0; i < 32; ++i) bits |= (mi[i] ? 1u : 0u) << i;
    }
    mp[w] = bits;
    return;
  }
  const f32x4* xr = (const f32x4*)(x + (size_t)row * DM);
  f32x4 v = xr[t];
  float s = v[0] + v[1] + v[2] + v[3];
  float q = v[0]*v[0] + v[1]*v[1] + v[2]*v[2] + v[3]*v[3];
  #pragma unroll
  for (int off = 32; off >= 1; off >>= 1) { s += __shfl_xor(s, off); q += __shfl_xor(q, off); }
  __shared__ float red[8];
  int wv = t >> 6;
  if ((t & 63) == 0) { red[wv] = s; red[4 + wv] = q; }
  __syncthreads();
  s = red[0] + red[1] + red[2] + red[3];
  q = red[4] + red[5] + red[6] + red[7];
  float mu = s * (1.0f / DM);
  float var = q * (1.0f / DM) - mu * mu;
  float rs = rsqrtf(var + 1e-5f);
  f32x4 sv = ((const f32x4*)sc)[t], bv = ((const f32x4*)bi)[t];
  ushort4v o;
  #pragma unroll
  for (int j = 0; j < 4; ++j) o[j] = f2bf((v[j] - mu) * rs * sv[j] + bv[j]);
  *(ushort4v*)(out + (size_t)row * DM + t * 4) = o;
}

// ---------- GEMM v11: 128x128 dbuf pipelined (gemm5) + per-XCD 2D patches ---
// Round-3 verdict: the 256^2 8-phase port (gemm8) never beat this structure
// (722 vs 771 TF on W1) -- barrier-lockstep serializes LDS-read vs MFMA, and
// the counted-vmcnt only hides global staging, which isn't the constraint at
// K=1024. Reverted. Kept from round 3: compact per-XCD 2D patch swizzle,
// which cut FETCH 135->49 MB on gemm8; applied here to cut A-band re-fetch
// (round-0 W1 FETCH 64.8 MB vs ~24 ideal). 4(M) x 2(N) XCD patch grid,
// M-fast within patch; falls back to linear when grid not divisible.
// C[m,n] = sum_k A[m,k]*W[n,k] + bias[n], bf16, K-contiguous operands.
// 256 threads / 4 waves (2M x 2N), per-wave 64x64.
// Per tile T: stage(T+1)->buf^1, WAITVM(8) [tile T landed], barrier,
// 16 ds_read_b128 + 32-MFMA setprio cluster, lgkmcnt(0), barrier.
// EPI 0: fused QKV (N=3072): Q/K -> [B,H,L,dk], V -> [B,H,dk,L], LDS repack
// EPI 1: fast tanh-GELU -> bf16 [M,N], LDS repack coalesced stores
// EPI 2: f32 out = res + acc + bias      (Wo + residual)
// EPI 3: f32 out += acc + bias           (W2 accumulate)
template <int EPI>
__global__ __launch_bounds__(256, 2)
void gemm5(const unsigned short* __restrict__ A, const unsigned short* __restrict__ Bw,
           const float* __restrict__ bias, void* __restrict__ out0,
           void* __restrict__ out1, void* __restrict__ out2,
           const float* __restrict__ res, int N, int K) {
  __shared__ __align__(16) char smem[65536];  // 2 x 32KB
  const int t = threadIdx.x;
  const int w = t >> 6, ln = t & 63;
  const int wm = w >> 1, wn = w & 1;
  const int lg = ln >> 4, lc = ln & 15;

  // compact per-XCD 2D patches (bijective when nwg%8==0): XCD x owns a
  // (gx/4 Mtile) x (gy/2 Ntile) patch; within-patch temporal order M-fast so
  // the A-band is established in L2/L3 and reused across the patch's columns.
  int mt = blockIdx.x, nt = blockIdx.y;
  {
    const int gx = gridDim.x, gy = gridDim.y;
    if (((gx & 3) == 0) && ((gy & 1) == 0)) {
      int orig = nt * gx + mt;
      int xcd = orig & 7, idx = orig >> 3;
      const int pmt = gx >> 2, pnt = gy >> 1;
      mt = (xcd >> 1) * pmt + (idx % pmt);
      nt = (xcd & 1) * pnt + (idx / pmt);
      (void)pnt;
    }
  }
  const int m0 = mt * 128, n0 = nt * 128;
  const size_t rb = (size_t)K * 2;
  const int nk = K >> 6;

  // staging sources: slot i covers LDS bytes [i*4096,(i+1)*4096) of
  // [A 16KB | B 16KB]; rows 128B; source chunk pre-XOR-swizzled by row.
  const char* srcp[8];
  #pragma unroll
  for (int i = 0; i < 8; ++i) {
    int off = i * 4096 + t * 16;
    if (off < 16384) {
      int r = off >> 7, c = (off >> 4) & 7;
      srcp[i] = (const char*)A + (size_t)(m0 + r) * rb + ((c ^ (r & 7)) << 4);
    } else {
      int ob = off - 16384;
      int r = ob >> 7, c = (ob >> 4) & 7;
      srcp[i] = (const char*)Bw + (size_t)(n0 + r) * rb + ((c ^ (r & 7)) << 4);
    }
  }
  auto stage8 = [&](int tile) {
    char* db = smem + ((tile & 1) << 15) + t * 16;
    const size_t ko = (size_t)tile << 7;
    #pragma unroll
    for (int i = 0; i < 8; ++i) gload_lds16(srcp[i] + ko, db + i * 4096);
  };

  // hoisted LDS read byte-offsets (loop-invariant, XOR-swizzled)
  int aoff[4][2], boff[4][2];
  #pragma unroll
  for (int x_ = 0; x_ < 4; ++x_)
    #pragma unroll
    for (int kk = 0; kk < 2; ++kk) {
      int ra = wm * 64 + x_ * 16 + lc;
      aoff[x_][kk] = ra * 128 + (((kk * 4 + lg) ^ (ra & 7)) << 4);
      int rn = wn * 64 + x_ * 16 + lc;
      boff[x_][kk] = 16384 + rn * 128 + (((kk * 4 + lg) ^ (rn & 7)) << 4);
    }

  f32x4 acc[4][4] = {};

  stage8(0);
  for (int T = 0; T < nk; ++T) {
    if (T + 1 < nk) stage8(T + 1);
    if (T == nk - 1) { WAITVM(0); } else { WAITVM(8); }  // tile T landed
    BARRIER;
    const char* buf = smem + ((T & 1) << 15);
    short8 afr[4][2], bfr[4][2];
    #pragma unroll
    for (int ni = 0; ni < 4; ++ni) {
      bfr[ni][0] = *(const short8*)(buf + boff[ni][0]);
      bfr[ni][1] = *(const short8*)(buf + boff[ni][1]);
    }
    #pragma unroll
    for (int mi = 0; mi < 4; ++mi) {
      afr[mi][0] = *(const short8*)(buf + aoff[mi][0]);
      afr[mi][1] = *(const short8*)(buf + aoff[mi][1]);
    }
    __builtin_amdgcn_s_setprio(1);
    #pragma unroll
    for (int mi = 0; mi < 4; ++mi)
      #pragma unroll
      for (int ni = 0; ni < 4; ++ni) {
        acc[mi][ni] = MFMA16(afr[mi][0], bfr[ni][0], acc[mi][ni]);
        acc[mi][ni] = MFMA16(afr[mi][1], bfr[ni][1], acc[mi][ni]);
      }
    __builtin_amdgcn_s_setprio(0);
    WAITLGKM0;   // my reads of buf[T&1] retired
    BARRIER;     // ALL waves' reads retired -> stage(T+2) may overwrite it
  }
  __syncthreads();  // epilogue overlay safety

  // ---- epilogue: row = m0+wm*64+mi*16+lg*4+rr, col = n0+wn*64+ni*16+lc
  const int colb = n0 + wn * 64 + lc;
  const int rowb = m0 + wm * 64 + lg * 4;
  if constexpr (EPI >= 2) {
    #pragma unroll
    for (int ni = 0; ni < 4; ++ni) {
      int col = colb + ni * 16;
      float bv = bias[col];
      #pragma unroll
      for (int mi = 0; mi < 4; ++mi)
        #pragma unroll
        for (int rr = 0; rr < 4; ++rr) {
          int row = rowb + mi * 16 + rr;
          float v = acc[mi][ni][rr] + bv;
          if constexpr (EPI == 2)
            ((float*)out0)[(size_t)row * N + col] = res[(size_t)row * N + col] + v;
          else
            ((float*)out0)[(size_t)row * N + col] += v;
        }
    }
  } else {
    short* sl = (short*)(smem + w * 9216);  // 4 x 9216 = 36KB <= 64KB
    const bool isV = (EPI == 0) && (n0 + wn * 64 >= 2048);
    #pragma unroll
    for (int ni = 0; ni < 4; ++ni) {
      float bv = bias[colb + ni * 16];
      #pragma unroll
      for (int mi = 0; mi < 4; ++mi)
        #pragma unroll
        for (int rr = 0; rr < 4; ++rr) {
          int row_l = mi * 16 + lg * 4 + rr;
          int col_l = ni * 16 + lc;
          float v = acc[mi][ni][rr] + bv;
          if constexpr (EPI == 1) {
            float u2 = v * v;
            float mexp = v * (-2.302206744f - 0.102953795f * u2);
            v = v / (1.0f + exp2f(mexp));
          }
          if (isV) sl[col_l * 72 + row_l] = (short)f2bf(v);
          else     sl[row_l * 72 + col_l] = (short)f2bf(v);
        }
    }
    const int s8 = ln >> 3, c8 = ln & 7;
    if constexpr (EPI == 0) {
      const int b_ = m0 >> 10;
      const int l0 = (m0 & 1023) + wm * 64;
      const int h_ = ((n0 + wn * 64) >> 6) & 15;
      const size_t bh = (size_t)(b_ * NH + h_);
      if (n0 + wn * 64 < 2048) {
        char* dst = (char*)((n0 + wn * 64 < 1024) ? out0 : out1) + (((bh << 10) + l0) << 7);
        #pragma unroll
        for (int j = 0; j < 8; ++j) {
          short8 v8 = *(const short8*)(sl + (j * 8 + s8) * 72 + c8 * 8);
          *(short8*)(dst + j * 1024 + ln * 16) = v8;
        }
      } else {
        char* dst = (char*)out2 + bh * 131072 + l0 * 2 + c8 * 16;
        #pragma unroll
        for (int j = 0; j < 8; ++j) {
          short8 v8 = *(const short8*)(sl + (j * 8 + s8) * 72 + c8 * 8);
          *(short8*)(dst + (size_t)(j * 8 + s8) * 2048) = v8;
        }
      }
    } else {
      char* dst = (char*)out0 + (size_t)(m0 + wm * 64) * ((size_t)N * 2) +
                  (size_t)(n0 + wn * 64) * 2 + c8 * 16;
      #pragma unroll
      for (int j = 0; j < 8; ++j) {
        short8 v8 = *(const short8*)(sl + (j * 8 + s8) * 72 + c8 * 8);
        *(short8*)(dst + (size_t)(j * 8 + s8) * ((size_t)N * 2)) = v8;
      }
    }
  }
}

// ---------- flash attention (r2 structure, unchanged) ----------
__global__ __launch_bounds__(512) void attn_kernel(const unsigned short* __restrict__ Q,
                                                   const unsigned short* __restrict__ Kb,
                                                   const unsigned short* __restrict__ Vt,
                                                   const unsigned* __restrict__ mp,
                                                   unsigned short* __restrict__ ctx) {
  __shared__ __align__(16) char kv[2][16384];      // [K tile 8KB | V tile 8KB] x2
  __shared__ __align__(16) short plds[8][16][72];  // per-wave P tile, padded rows
  const int t = threadIdx.x, wv = t >> 6, ln = t & 63;
  const int bid = blockIdx.x;
  const int wg = (bid & 7) * 128 + (bid >> 3);     // XCD swizzle (grid 1024)
  const int qt = wg & 7, h_ = (wg >> 3) & 15, b_ = wg >> 7;
  const int bh = b_ * NH + h_;
  const int lg = ln >> 4, lc = ln & 15;
  const int qrow0 = qt * 128 + wv * 16;

  const unsigned short* qbase = Q + ((size_t)bh * LL + qrow0) * DK;
  short8 qf0 = *(const short8*)(qbase + (size_t)lc * DK + lg * 8);
  short8 qf1 = *(const short8*)(qbase + (size_t)lc * DK + 32 + lg * 8);

  short8 onesf;
  #pragma unroll
  for (int j = 0; j < 8; ++j) onesf[j] = (short)0x3F80;  // bf16 1.0

  f32x4 o[4] = {};
  f32x4 o_l = {};  // row sums via ones-column MFMA

  const char* kg = (const char*)(Kb + (size_t)bh * LL * DK);
  const char* vg = (const char*)(Vt + (size_t)bh * DK * LL);
  const int srow = ln >> 3;
  const int gc = (ln & 7) ^ srow;
  const char* ksrc = kg + (size_t)(wv * 8 + srow) * 128 + gc * 16;
  const char* vsrc = vg + (size_t)(wv * 8 + srow) * 2048 + gc * 16;

  const unsigned* mrow = mp + ((size_t)b_ * LL + qrow0) * 32;

  gload_lds16(ksrc, kv[0] + wv * 1024);
  gload_lds16(vsrc, kv[0] + 8192 + wv * 1024);
  __syncthreads();

  int cur = 0;
  for (int kt = 0; kt < 16; ++kt) {
    if (kt < 15) {
      gload_lds16(ksrc + (size_t)(kt + 1) * 8192, kv[cur ^ 1] + wv * 1024);
      gload_lds16(vsrc + (size_t)(kt + 1) * 128, kv[cur ^ 1] + 8192 + wv * 1024);
    }
    const char* kb_ = kv[cur];
    const char* vb_ = kv[cur] + 8192;
    f32x4 s[4] = {};
    #pragma unroll
    for (int c = 0; c < 4; ++c) {
      int row = c * 16 + lc;
      short8 k0 = *(const short8*)(kb_ + row * 128 + ((lg) ^ (row & 7)) * 16);
      short8 k1 = *(const short8*)(kb_ + row * 128 + ((4 + lg) ^ (row & 7)) * 16);
      s[c] = MFMA16(qf0, k0, s[c]);
      s[c] = MFMA16(qf1, k1, s[c]);
    }
    unsigned wrd[4][2];
    #pragma unroll
    for (int r = 0; r < 4; ++r) {
      const unsigned* mr = mrow + (size_t)(lg * 4 + r) * 32 + kt * 2;
      wrd[r][0] = mr[0]; wrd[r][1] = mr[1];
    }
    #pragma unroll
    for (int c = 0; c < 4; ++c)
      #pragma unroll
      for (int r = 0; r < 4; ++r) {
        bool mk = (wrd[r][c >> 1] >> ((c & 1) * 16 + lc)) & 1;
        float p = mk ? 0.0f : exp2f(fmaf(s[c][r], 0.18033688011112f, -16.0f));
        plds[wv][lg * 4 + r][c * 16 + lc] = (short)f2bf(p);
      }
    #pragma unroll
    for (int kk = 0; kk < 2; ++kk) {
      short8 pf = *(const short8*)&plds[wv][lc][kk * 32 + lg * 8];
      o_l = MFMA16(pf, onesf, o_l);
      #pragma unroll
      for (int dt = 0; dt < 4; ++dt) {
        int row = dt * 16 + lc;
        short8 vf = *(const short8*)(vb_ + row * 128 + ((kk * 4 + lg) ^ (row & 7)) * 16);
        o[dt] = MFMA16(pf, vf, o[dt]);
      }
    }
    __syncthreads();
    cur ^= 1;
  }
  #pragma unroll
  for (int r = 0; r < 4; ++r) {
    float l = o_l[r];
    float inv = (l > 0.0f) ? 1.0f / l : 0.0f;
    size_t trow = (size_t)b_ * LL + qt * 128 + wv * 16 + lg * 4 + r;
    #pragma unroll
    for (int dt = 0; dt < 4; ++dt)
      ctx[trow * DM + h_ * 64 + dt * 16 + lc] = f2bf(o[dt][r] * inv);
  }
}

// ---------- launch ----------
extern "C" void kernel_launch(void* const* d_in, const int* in_sizes, int n_in,
                              void* d_out, int out_size, void* d_ws, size_t ws_size,
                              hipStream_t stream) {
  const float* x   = (const float*)d_in[0];
  const void*  msk = d_in[1];
  const float* Wq = (const float*)d_in[2],  *bq = (const float*)d_in[3];
  const float* Wk = (const float*)d_in[4],  *bk = (const float*)d_in[5];
  const float* Wv = (const float*)d_in[6],  *bv = (const float*)d_in[7];
  const float* Wo = (const float*)d_in[8],  *bo = (const float*)d_in[9];
  const float* l1s = (const float*)d_in[10], *l1b = (const float*)d_in[11];
  const float* l2s = (const float*)d_in[12], *l2b = (const float*)d_in[13];
  const float* W1 = (const float*)d_in[14], *b1 = (const float*)d_in[15];
  const float* W2 = (const float*)d_in[16], *b2 = (const float*)d_in[17];
  float* out = (float*)d_out;
  char* ws = (char*)d_ws;
  const size_t MB = 1u << 20;

  unsigned short* wqkv = (unsigned short*)(ws + 0 * MB);  // 6MB (Wq|Wk|Wv rows)
  unsigned short* wob = (unsigned short*)(ws + 6 * MB);   // 2MB
  unsigned short* w1b = (unsigned short*)(ws + 8 * MB);   // 8MB
  unsigned short* w2b = (unsigned short*)(ws + 16 * MB);  // 8MB
  unsigned short* xn  = (unsigned short*)(ws + 24 * MB);  // 16MB (reused as ctx)
  unsigned short* qb  = (unsigned short*)(ws + 40 * MB);  // 16MB (reused as xn2)
  unsigned short* kb  = (unsigned short*)(ws + 56 * MB);  // 16MB
  unsigned short* vtb = (unsigned short*)(ws + 72 * MB);  // 16MB
  unsigned*       mpk = (unsigned*)(ws + 88 * MB);        // 1MB
  float*          bqkv = (float*)(ws + 89 * MB);          // 12KB
  int*            flg = (int*)(ws + 89 * MB + 65536);     // 4B
  unsigned short* ctx = xn;
  unsigned short* xn2 = qb;
  unsigned short* hb  = (unsigned short*)(ws + 90 * MB);  // mchunk*4096*2

  int mchunk;
  size_t avail = (ws_size > 90 * MB) ? ws_size - 90 * MB : 0;
  if      (avail >= 64 * MB) mchunk = 8192;
  else if (avail >= 16 * MB) mchunk = 2048;
  else if (avail >= 4 * MB)  mchunk = 512;
  else                       mchunk = 256;

  // fused prep: weights -> bf16, bias concat, mask dtype detect
  prep_kernel<<<6157, 256, 0, stream>>>(Wq, Wk, Wv, Wo, W1, W2, bq, bk, bv,
                                        wqkv, wob, w1b, w2b, bqkv,
                                        (const unsigned*)msk, flg);

  // LN1 + mask pack (1024 extra blocks)
  ln_kernel<<<TT + 1024, 256, 0, stream>>>(x, l1s, l1b, xn, msk, mpk, flg, 1024);

  // fused QKV projection (M=8192, N=3072, K=1024)
  gemm5<0><<<dim3(64, 24), 256, 0, stream>>>(xn, wqkv, bqkv, qb, kb, vtb,
                                             nullptr, 3072, DM);

  // attention (1024 blocks: 8 b * 16 h * 8 q-tiles of 128 rows)
  attn_kernel<<<1024, 512, 0, stream>>>(qb, kb, vtb, mpk, ctx);

  // Wo + residual -> d_out (fp32)
  gemm5<2><<<dim3(64, 8), 256, 0, stream>>>(ctx, wob, bo, out, nullptr, nullptr,
                                            x, DM, DM);

  // LN2
  ln_kernel<<<TT, 256, 0, stream>>>(out, l2s, l2b, xn2, nullptr, nullptr, flg, 0);

  // FFN, chunked over M to bound scratch
  for (int off = 0; off < TT; off += mchunk) {
    gemm5<1><<<dim3(mchunk / 128, 32), 256, 0, stream>>>(
        xn2 + (size_t)off * DM, w1b, b1, hb, nullptr, nullptr, nullptr, FF, DM);
    gemm5<3><<<dim3(mchunk / 128, 8), 256, 0, stream>>>(
        hb, w2b, b2, out + (size_t)off * DM, nullptr, nullptr, nullptr, DM, FF);
  }
}

// Round 5
// 383.450 us; speedup vs baseline: 1.0350x; 1.0211x over previous
//
#include <hip/hip_runtime.h>
#include <cstdint>
#include <cstddef>

// ---------- types ----------
typedef __attribute__((ext_vector_type(8))) short short8;     // 8 x bf16
typedef __attribute__((ext_vector_type(4))) float f32x4;
typedef __attribute__((ext_vector_type(4))) unsigned short ushort4v;

#define DEVI __device__ __forceinline__

DEVI unsigned short f2bf(float f) {  // RNE f32 -> bf16 bits
  union { float f; unsigned u; } x; x.f = f;
  unsigned r = x.u + 0x7fffu + ((x.u >> 16) & 1u);
  return (unsigned short)(r >> 16);
}

#define MFMA16(a, b, c) __builtin_amdgcn_mfma_f32_16x16x32_bf16(a, b, c, 0, 0, 0)
#define FENCE asm volatile("" ::: "memory")
#define WAITVM(n) asm volatile("s_waitcnt vmcnt(" #n ")" ::: "memory")
#define WAITLGKM0 asm volatile("s_waitcnt lgkmcnt(0)" ::: "memory")
#define BARRIER do { FENCE; __builtin_amdgcn_s_barrier(); FENCE; } while (0)

typedef __attribute__((address_space(1))) const void g_void;
typedef __attribute__((address_space(3))) void lds_void;
DEVI void gload_lds16(const void* g, void* l) {
  __builtin_amdgcn_global_load_lds((g_void*)g, (lds_void*)l, 16, 0, 0);
}

// ---------- constants ----------
static constexpr int DM = 1024;   // d_model
static constexpr int NH = 16;     // heads
static constexpr int DK = 64;     // head dim
static constexpr int FF = 4096;   // d_ff
static constexpr int BB = 8;      // batch
static constexpr int LL = 1024;   // seq
static constexpr int TT = BB * LL; // 8192 tokens

// ---------- fused prep: 6 weight cvts + QKV bias concat + mask dtype detect ----
__global__ __launch_bounds__(256) void prep_kernel(
    const float* __restrict__ Wq, const float* __restrict__ Wk,
    const float* __restrict__ Wv, const float* __restrict__ Wo,
    const float* __restrict__ W1, const float* __restrict__ W2,
    const float* __restrict__ bq, const float* __restrict__ bk,
    const float* __restrict__ bv,
    unsigned short* __restrict__ wqkv, unsigned short* __restrict__ wob,
    unsigned short* __restrict__ w1b, unsigned short* __restrict__ w2b,
    float* __restrict__ bqkv, const unsigned* __restrict__ mask,
    int* __restrict__ flag) {
  int b = blockIdx.x;
  if (b < 6144) {
    int i = b * 256 + threadIdx.x;
    const float* src; unsigned short* dst; int li;
    if (i < 131072)      { src = Wq; dst = wqkv;             li = i; }
    else if (i < 262144) { src = Wk; dst = wqkv + (1 << 20); li = i - 131072; }
    else if (i < 393216) { src = Wv; dst = wqkv + (2 << 20); li = i - 262144; }
    else if (i < 524288) { src = Wo; dst = wob;              li = i - 393216; }
    else if (i < 1048576){ src = W1; dst = w1b;              li = i - 524288; }
    else                 { src = W2; dst = w2b;              li = i - 1048576; }
    const f32x4* s4 = (const f32x4*)src;
    f32x4 a = s4[li * 2], c = s4[li * 2 + 1];
    short8 o;
    o[0] = (short)f2bf(a[0]); o[1] = (short)f2bf(a[1]);
    o[2] = (short)f2bf(a[2]); o[3] = (short)f2bf(a[3]);
    o[4] = (short)f2bf(c[0]); o[5] = (short)f2bf(c[1]);
    o[6] = (short)f2bf(c[2]); o[7] = (short)f2bf(c[3]);
    *(short8*)(dst + (size_t)li * 8) = o;
  } else if (b < 6156) {
    int i = (b - 6144) * 256 + threadIdx.x;  // 3072
    bqkv[i] = (i < 1024) ? bq[i] : (i < 2048 ? bk[i - 1024] : bv[i - 2048]);
  } else {
    unsigned a = 0;
    for (int i = threadIdx.x; i < 4096; i += 256) a |= mask[i];
    #pragma unroll
    for (int off = 32; off >= 1; off >>= 1) a |= __shfl_xor(a, off);
    __shared__ unsigned sh[4];
    if ((threadIdx.x & 63) == 0) sh[threadIdx.x >> 6] = a;
    __syncthreads();
    if (threadIdx.x == 0) {
      unsigned o = sh[0] | sh[1] | sh[2] | sh[3];
      flag[0] = (o & 0xFEFEFEFEu) ? 2 : ((o & 0xFFFFFF00u) ? 1 : 0);
    }
  }
}

// ---------- LayerNorm (fp32 in, bf16 out) + optional mask-pack blocks ----------
__global__ __launch_bounds__(256) void ln_kernel(const float* __restrict__ x,
                                                 const float* __restrict__ sc,
                                                 const float* __restrict__ bi,
                                                 unsigned short* __restrict__ out,
                                                 const void* __restrict__ mask,
                                                 unsigned* __restrict__ mp,
                                                 const int* __restrict__ flag,
                                                 int npack) {
  int row = blockIdx.x;
  int t = threadIdx.x;
  if (row >= TT) {
    int w = (row - TT) * 256 + t;   // word over B*L*(L/32) = 262144
    int cls = flag[0];
    unsigned bits = 0u;
    if (cls == 1) {
      const unsigned char* mb = (const unsigned char*)mask + (size_t)w * 32;
      #pragma unroll 8
      for (int i = 0; i < 32; ++i) bits |= (mb[i] ? 1u : 0u) << i;
    } else {
      const unsigned* mi = (const unsigned*)mask + (size_t)w * 32;
      #pragma unroll 8
      for (int i = 0; i < 32; ++i) bits |= (mi[i] ? 1u : 0u) << i;
    }
    mp[w] = bits;
    return;
  }
  const f32x4* xr = (const f32x4*)(x + (size_t)row * DM);
  f32x4 v = xr[t];
  float s = v[0] + v[1] + v[2] + v[3];
  float q = v[0]*v[0] + v[1]*v[1] + v[2]*v[2] + v[3]*v[3];
  #pragma unroll
  for (int off = 32; off >= 1; off >>= 1) { s += __shfl_xor(s, off); q += __shfl_xor(q, off); }
  __shared__ float red[8];
  int wv = t >> 6;
  if ((t & 63) == 0) { red[wv] = s; red[4 + wv] = q; }
  __syncthreads();
  s = red[0] + red[1] + red[2] + red[3];
  q = red[4] + red[5] + red[6] + red[7];
  float mu = s * (1.0f / DM);
  float var = q * (1.0f / DM) - mu * mu;
  float rs = rsqrtf(var + 1e-5f);
  f32x4 sv = ((const f32x4*)sc)[t], bv = ((const f32x4*)bi)[t];
  ushort4v o;
  #pragma unroll
  for (int j = 0; j < 4; ++j) o[j] = f2bf((v[j] - mu) * rs * sv[j] + bv[j]);
  *(ushort4v*)(out + (size_t)row * DM + t * 4) = o;
}

// ---------- GEMM v9: 128x128, dbuf pipelined, 2 blocks/CU (round-0 proven) ---
// K=1024 regime verdict (rounds 1-4): the 256^2 8-phase template's verified
// gain at K=1024 is only ~+10% (m248: 2ph 666 vs full 8ph 848); this 2-phase
// structure at 771 TF is within that band, and both my 8-phase ports measured
// BELOW it (722). Patch swizzle also hurt here (FETCH 64.8->82MB). Reverted
// to the round-0 exact structure: linear grid, x-fast (B-panel reuse).
template <int EPI>
__global__ __launch_bounds__(256, 2)
void gemm5(const unsigned short* __restrict__ A, const unsigned short* __restrict__ Bw,
           const float* __restrict__ bias, void* __restrict__ out0,
           void* __restrict__ out1, void* __restrict__ out2,
           const float* __restrict__ res, int N, int K) {
  __shared__ __align__(16) char smem[65536];  // 2 x 32KB
  const int t = threadIdx.x;
  const int w = t >> 6, ln = t & 63;
  const int wm = w >> 1, wn = w & 1;
  const int lg = ln >> 4, lc = ln & 15;
  const int m0 = blockIdx.x * 128, n0 = blockIdx.y * 128;
  const size_t rb = (size_t)K * 2;
  const int nk = K >> 6;

  const char* srcp[8];
  #pragma unroll
  for (int i = 0; i < 8; ++i) {
    int off = i * 4096 + t * 16;
    if (off < 16384) {
      int r = off >> 7, c = (off >> 4) & 7;
      srcp[i] = (const char*)A + (size_t)(m0 + r) * rb + ((c ^ (r & 7)) << 4);
    } else {
      int ob = off - 16384;
      int r = ob >> 7, c = (ob >> 4) & 7;
      srcp[i] = (const char*)Bw + (size_t)(n0 + r) * rb + ((c ^ (r & 7)) << 4);
    }
  }
  auto stage8 = [&](int tile) {
    char* db = smem + ((tile & 1) << 15) + t * 16;
    const size_t ko = (size_t)tile << 7;
    #pragma unroll
    for (int i = 0; i < 8; ++i) gload_lds16(srcp[i] + ko, db + i * 4096);
  };

  int aoff[4][2], boff[4][2];
  #pragma unroll
  for (int x_ = 0; x_ < 4; ++x_)
    #pragma unroll
    for (int kk = 0; kk < 2; ++kk) {
      int ra = wm * 64 + x_ * 16 + lc;
      aoff[x_][kk] = ra * 128 + (((kk * 4 + lg) ^ (ra & 7)) << 4);
      int rn = wn * 64 + x_ * 16 + lc;
      boff[x_][kk] = 16384 + rn * 128 + (((kk * 4 + lg) ^ (rn & 7)) << 4);
    }

  f32x4 acc[4][4] = {};

  stage8(0);
  for (int T = 0; T < nk; ++T) {
    if (T + 1 < nk) stage8(T + 1);
    if (T == nk - 1) { WAITVM(0); } else { WAITVM(8); }  // tile T landed
    BARRIER;
    const char* buf = smem + ((T & 1) << 15);
    short8 afr[4][2], bfr[4][2];
    #pragma unroll
    for (int ni = 0; ni < 4; ++ni) {
      bfr[ni][0] = *(const short8*)(buf + boff[ni][0]);
      bfr[ni][1] = *(const short8*)(buf + boff[ni][1]);
    }
    #pragma unroll
    for (int mi = 0; mi < 4; ++mi) {
      afr[mi][0] = *(const short8*)(buf + aoff[mi][0]);
      afr[mi][1] = *(const short8*)(buf + aoff[mi][1]);
    }
    __builtin_amdgcn_s_setprio(1);
    #pragma unroll
    for (int mi = 0; mi < 4; ++mi)
      #pragma unroll
      for (int ni = 0; ni < 4; ++ni) {
        acc[mi][ni] = MFMA16(afr[mi][0], bfr[ni][0], acc[mi][ni]);
        acc[mi][ni] = MFMA16(afr[mi][1], bfr[ni][1], acc[mi][ni]);
      }
    __builtin_amdgcn_s_setprio(0);
    WAITLGKM0;   // my reads of buf[T&1] retired
    BARRIER;     // ALL waves' reads retired -> stage(T+2) may overwrite it
  }
  __syncthreads();  // epilogue overlay safety

  const int colb = n0 + wn * 64 + lc;
  const int rowb = m0 + wm * 64 + lg * 4;
  if constexpr (EPI >= 2) {
    #pragma unroll
    for (int ni = 0; ni < 4; ++ni) {
      int col = colb + ni * 16;
      float bv = bias[col];
      #pragma unroll
      for (int mi = 0; mi < 4; ++mi)
        #pragma unroll
        for (int rr = 0; rr < 4; ++rr) {
          int row = rowb + mi * 16 + rr;
          float v = acc[mi][ni][rr] + bv;
          if constexpr (EPI == 2)
            ((float*)out0)[(size_t)row * N + col] = res[(size_t)row * N + col] + v;
          else
            ((float*)out0)[(size_t)row * N + col] += v;
        }
    }
  } else {
    short* sl = (short*)(smem + w * 9216);  // 4 x 9216 = 36KB <= 64KB
    const bool isV = (EPI == 0) && (n0 + wn * 64 >= 2048);
    #pragma unroll
    for (int ni = 0; ni < 4; ++ni) {
      float bv = bias[colb + ni * 16];
      #pragma unroll
      for (int mi = 0; mi < 4; ++mi)
        #pragma unroll
        for (int rr = 0; rr < 4; ++rr) {
          int row_l = mi * 16 + lg * 4 + rr;
          int col_l = ni * 16 + lc;
          float v = acc[mi][ni][rr] + bv;
          if constexpr (EPI == 1) {
            float u2 = v * v;
            float mexp = v * (-2.302206744f - 0.102953795f * u2);
            v = v / (1.0f + exp2f(mexp));
          }
          if (isV) sl[col_l * 72 + row_l] = (short)f2bf(v);
          else     sl[row_l * 72 + col_l] = (short)f2bf(v);
        }
    }
    const int s8 = ln >> 3, c8 = ln & 7;
    if constexpr (EPI == 0) {
      const int b_ = m0 >> 10;
      const int l0 = (m0 & 1023) + wm * 64;
      const int h_ = ((n0 + wn * 64) >> 6) & 15;
      const size_t bh = (size_t)(b_ * NH + h_);
      if (n0 + wn * 64 < 2048) {
        char* dst = (char*)((n0 + wn * 64 < 1024) ? out0 : out1) + (((bh << 10) + l0) << 7);
        #pragma unroll
        for (int j = 0; j < 8; ++j) {
          short8 v8 = *(const short8*)(sl + (j * 8 + s8) * 72 + c8 * 8);
          *(short8*)(dst + j * 1024 + ln * 16) = v8;
        }
      } else {
        char* dst = (char*)out2 + bh * 131072 + l0 * 2 + c8 * 16;
        #pragma unroll
        for (int j = 0; j < 8; ++j) {
          short8 v8 = *(const short8*)(sl + (j * 8 + s8) * 72 + c8 * 8);
          *(short8*)(dst + (size_t)(j * 8 + s8) * 2048) = v8;
        }
      }
    } else {
      char* dst = (char*)out0 + (size_t)(m0 + wm * 64) * ((size_t)N * 2) +
                  (size_t)(n0 + wn * 64) * 2 + c8 * 16;
      #pragma unroll
      for (int j = 0; j < 8; ++j) {
        short8 v8 = *(const short8*)(sl + (j * 8 + s8) * 72 + c8 * 8);
        *(short8*)(dst + (size_t)(j * 8 + s8) * ((size_t)N * 2)) = v8;
      }
    }
  }
}

// ---------- flash attention: counted-vmcnt dbuf (no per-iter vmcnt(0) drain) -
// Round-4 change: the old loop ended each of 16 iterations with
// __syncthreads(), which lowers to s_waitcnt vmcnt(0) lgkmcnt(0); s_barrier --
// a full drain of the just-issued K/V prefetch (the documented m97 barrier-
// drain stall). Replaced with gemm5's proven discipline: issue stage(kt+1),
// WAITVM(2) [wait only the PREVIOUS tile's 2 loads; new 2 stay in flight],
// barrier [tile complete collectively], compute, lgkmcnt(0) [my LDS reads of
// kv[cur] retired], barrier [WAR-safe to overwrite next iter]. Mask
// global-loads retire via their in-phase uses, so vmcnt counts stay exact.
__global__ __launch_bounds__(512) void attn_kernel(const unsigned short* __restrict__ Q,
                                                   const unsigned short* __restrict__ Kb,
                                                   const unsigned short* __restrict__ Vt,
                                                   const unsigned* __restrict__ mp,
                                                   unsigned short* __restrict__ ctx) {
  __shared__ __align__(16) char kv[2][16384];      // [K tile 8KB | V tile 8KB] x2
  __shared__ __align__(16) short plds[8][16][72];  // per-wave P tile, padded rows
  const int t = threadIdx.x, wv = t >> 6, ln = t & 63;
  const int bid = blockIdx.x;
  const int wg = (bid & 7) * 128 + (bid >> 3);     // XCD swizzle (grid 1024)
  const int qt = wg & 7, h_ = (wg >> 3) & 15, b_ = wg >> 7;
  const int bh = b_ * NH + h_;
  const int lg = ln >> 4, lc = ln & 15;
  const int qrow0 = qt * 128 + wv * 16;

  const unsigned short* qbase = Q + ((size_t)bh * LL + qrow0) * DK;
  short8 qf0 = *(const short8*)(qbase + (size_t)lc * DK + lg * 8);
  short8 qf1 = *(const short8*)(qbase + (size_t)lc * DK + 32 + lg * 8);

  short8 onesf;
  #pragma unroll
  for (int j = 0; j < 8; ++j) onesf[j] = (short)0x3F80;  // bf16 1.0

  f32x4 o[4] = {};
  f32x4 o_l = {};  // row sums via ones-column MFMA

  const char* kg = (const char*)(Kb + (size_t)bh * LL * DK);
  const char* vg = (const char*)(Vt + (size_t)bh * DK * LL);
  const int srow = ln >> 3;
  const int gc = (ln & 7) ^ srow;
  const char* ksrc = kg + (size_t)(wv * 8 + srow) * 128 + gc * 16;
  const char* vsrc = vg + (size_t)(wv * 8 + srow) * 2048 + gc * 16;

  const unsigned* mrow = mp + ((size_t)b_ * LL + qrow0) * 32;

  gload_lds16(ksrc, kv[0] + wv * 1024);
  gload_lds16(vsrc, kv[0] + 8192 + wv * 1024);
  __syncthreads();   // prologue: tile 0 landed (drains vmcnt)

  int cur = 0;
  for (int kt = 0; kt < 16; ++kt) {
    if (kt < 15) {
      gload_lds16(ksrc + (size_t)(kt + 1) * 8192, kv[cur ^ 1] + wv * 1024);
      gload_lds16(vsrc + (size_t)(kt + 1) * 128, kv[cur ^ 1] + 8192 + wv * 1024);
      WAITVM(2);   // previous tile's 2 loads landed; new 2 stay in flight
    } else {
      WAITVM(0);   // last tile: drain the final prefetch
    }
    BARRIER;       // all waves' stages landed -> kv[cur] complete
    const char* kb_ = kv[cur];
    const char* vb_ = kv[cur] + 8192;
    f32x4 s[4] = {};
    #pragma unroll
    for (int c = 0; c < 4; ++c) {
      int row = c * 16 + lc;
      short8 k0 = *(const short8*)(kb_ + row * 128 + ((lg) ^ (row & 7)) * 16);
      short8 k1 = *(const short8*)(kb_ + row * 128 + ((4 + lg) ^ (row & 7)) * 16);
      s[c] = MFMA16(qf0, k0, s[c]);
      s[c] = MFMA16(qf1, k1, s[c]);
    }
    unsigned wrd[4][2];
    #pragma unroll
    for (int r = 0; r < 4; ++r) {
      const unsigned* mr = mrow + (size_t)(lg * 4 + r) * 32 + kt * 2;
      wrd[r][0] = mr[0]; wrd[r][1] = mr[1];
    }
    #pragma unroll
    for (int c = 0; c < 4; ++c)
      #pragma unroll
      for (int r = 0; r < 4; ++r) {
        bool mk = (wrd[r][c >> 1] >> ((c & 1) * 16 + lc)) & 1;
        float p = mk ? 0.0f : exp2f(fmaf(s[c][r], 0.18033688011112f, -16.0f));
        plds[wv][lg * 4 + r][c * 16 + lc] = (short)f2bf(p);
      }
    #pragma unroll
    for (int kk = 0; kk < 2; ++kk) {
      short8 pf = *(const short8*)&plds[wv][lc][kk * 32 + lg * 8];
      o_l = MFMA16(pf, onesf, o_l);
      #pragma unroll
      for (int dt = 0; dt < 4; ++dt) {
        int row = dt * 16 + lc;
        short8 vf = *(const short8*)(vb_ + row * 128 + ((kk * 4 + lg) ^ (row & 7)) * 16);
        o[dt] = MFMA16(pf, vf, o[dt]);
      }
    }
    WAITLGKM0;     // my LDS reads of kv[cur] retired
    BARRIER;       // all waves done with kv[cur] -> next stage may overwrite
    cur ^= 1;
  }
  #pragma unroll
  for (int r = 0; r < 4; ++r) {
    float l = o_l[r];
    float inv = (l > 0.0f) ? 1.0f / l : 0.0f;
    size_t trow = (size_t)b_ * LL + qt * 128 + wv * 16 + lg * 4 + r;
    #pragma unroll
    for (int dt = 0; dt < 4; ++dt)
      ctx[trow * DM + h_ * 64 + dt * 16 + lc] = f2bf(o[dt][r] * inv);
  }
}

// ---------- launch ----------
extern "C" void kernel_launch(void* const* d_in, const int* in_sizes, int n_in,
                              void* d_out, int out_size, void* d_ws, size_t ws_size,
                              hipStream_t stream) {
  const float* x   = (const float*)d_in[0];
  const void*  msk = d_in[1];
  const float* Wq = (const float*)d_in[2],  *bq = (const float*)d_in[3];
  const float* Wk = (const float*)d_in[4],  *bk = (const float*)d_in[5];
  const float* Wv = (const float*)d_in[6],  *bv = (const float*)d_in[7];
  const float* Wo = (const float*)d_in[8],  *bo = (const float*)d_in[9];
  const float* l1s = (const float*)d_in[10], *l1b = (const float*)d_in[11];
  const float* l2s = (const float*)d_in[12], *l2b = (const float*)d_in[13];
  const float* W1 = (const float*)d_in[14], *b1 = (const float*)d_in[15];
  const float* W2 = (const float*)d_in[16], *b2 = (const float*)d_in[17];
  float* out = (float*)d_out;
  char* ws = (char*)d_ws;
  const size_t MB = 1u << 20;

  unsigned short* wqkv = (unsigned short*)(ws + 0 * MB);  // 6MB (Wq|Wk|Wv rows)
  unsigned short* wob = (unsigned short*)(ws + 6 * MB);   // 2MB
  unsigned short* w1b = (unsigned short*)(ws + 8 * MB);   // 8MB
  unsigned short* w2b = (unsigned short*)(ws + 16 * MB);  // 8MB
  unsigned short* xn  = (unsigned short*)(ws + 24 * MB);  // 16MB (reused as ctx)
  unsigned short* qb  = (unsigned short*)(ws + 40 * MB);  // 16MB (reused as xn2)
  unsigned short* kb  = (unsigned short*)(ws + 56 * MB);  // 16MB
  unsigned short* vtb = (unsigned short*)(ws + 72 * MB);  // 16MB
  unsigned*       mpk = (unsigned*)(ws + 88 * MB);        // 1MB
  float*          bqkv = (float*)(ws + 89 * MB);          // 12KB
  int*            flg = (int*)(ws + 89 * MB + 65536);     // 4B
  unsigned short* ctx = xn;
  unsigned short* xn2 = qb;
  unsigned short* hb  = (unsigned short*)(ws + 90 * MB);  // mchunk*4096*2

  int mchunk;
  size_t avail = (ws_size > 90 * MB) ? ws_size - 90 * MB : 0;
  if      (avail >= 64 * MB) mchunk = 8192;
  else if (avail >= 16 * MB) mchunk = 2048;
  else if (avail >= 4 * MB)  mchunk = 512;
  else                       mchunk = 256;

  // fused prep: weights -> bf16, bias concat, mask dtype detect
  prep_kernel<<<6157, 256, 0, stream>>>(Wq, Wk, Wv, Wo, W1, W2, bq, bk, bv,
                                        wqkv, wob, w1b, w2b, bqkv,
                                        (const unsigned*)msk, flg);

  // LN1 + mask pack (1024 extra blocks)
  ln_kernel<<<TT + 1024, 256, 0, stream>>>(x, l1s, l1b, xn, msk, mpk, flg, 1024);

  // fused QKV projection (M=8192, N=3072, K=1024)
  gemm5<0><<<dim3(64, 24), 256, 0, stream>>>(xn, wqkv, bqkv, qb, kb, vtb,
                                             nullptr, 3072, DM);

  // attention (1024 blocks: 8 b * 16 h * 8 q-tiles of 128 rows)
  attn_kernel<<<1024, 512, 0, stream>>>(qb, kb, vtb, mpk, ctx);

  // Wo + residual -> d_out (fp32)
  gemm5<2><<<dim3(64, 8), 256, 0, stream>>>(ctx, wob, bo, out, nullptr, nullptr,
                                            x, DM, DM);

  // LN2
  ln_kernel<<<TT, 256, 0, stream>>>(out, l2s, l2b, xn2, nullptr, nullptr, flg, 0);

  // FFN, chunked over M to bound scratch
  for (int off = 0; off < TT; off += mchunk) {
    gemm5<1><<<dim3(mchunk / 128, 32), 256, 0, stream>>>(
        xn2 + (size_t)off * DM, w1b, b1, hb, nullptr, nullptr, nullptr, FF, DM);
    gemm5<3><<<dim3(mchunk / 128, 8), 256, 0, stream>>>(
        hb, w2b, b2, out + (size_t)off * DM, nullptr, nullptr, nullptr, DM, FF);
  }
}

// Round 6
// 380.257 us; speedup vs baseline: 1.0437x; 1.0084x over previous
//
#include <hip/hip_runtime.h>
#include <cstdint>
#include <cstddef>

// ---------- types ----------
typedef __attribute__((ext_vector_type(8))) short short8;     // 8 x bf16
typedef __attribute__((ext_vector_type(4))) float f32x4;
typedef __attribute__((ext_vector_type(4))) unsigned short ushort4v;

#define DEVI __device__ __forceinline__

DEVI unsigned short f2bf(float f) {  // RNE f32 -> bf16 bits
  union { float f; unsigned u; } x; x.f = f;
  unsigned r = x.u + 0x7fffu + ((x.u >> 16) & 1u);
  return (unsigned short)(r >> 16);
}

#define MFMA16(a, b, c) __builtin_amdgcn_mfma_f32_16x16x32_bf16(a, b, c, 0, 0, 0)
#define FENCE asm volatile("" ::: "memory")
#define WAITVM(n) asm volatile("s_waitcnt vmcnt(" #n ")" ::: "memory")
#define WAITLGKM0 asm volatile("s_waitcnt lgkmcnt(0)" ::: "memory")
#define BARRIER do { FENCE; __builtin_amdgcn_s_barrier(); FENCE; } while (0)

typedef __attribute__((address_space(1))) const void g_void;
typedef __attribute__((address_space(3))) void lds_void;
DEVI void gload_lds16(const void* g, void* l) {
  __builtin_amdgcn_global_load_lds((g_void*)g, (lds_void*)l, 16, 0, 0);
}

// ---------- constants ----------
static constexpr int DM = 1024;   // d_model
static constexpr int NH = 16;     // heads
static constexpr int DK = 64;     // head dim
static constexpr int FF = 4096;   // d_ff
static constexpr int BB = 8;      // batch
static constexpr int LL = 1024;   // seq
static constexpr int TT = BB * LL; // 8192 tokens

// ---------- fused phase-1: LN1 + mask-pack + weight cvt + bias concat -------
// Round-6 merge: prep and LN1 were serial launches but share no data deps
// except `flag`; pack blocks now self-detect the mask dtype with the same
// 16KB OR-scan (L2-broadcast after the first block, ~1-2us total). One
// launch instead of two removes a full serialization boundary.
// Block map: [0,TT) LN rows | [TT,TT+1024) mask-pack | [+6144) weight cvt |
// [+12) bias concat.
__global__ __launch_bounds__(256) void prep_ln1_kernel(
    const float* __restrict__ x, const float* __restrict__ sc,
    const float* __restrict__ bi, unsigned short* __restrict__ xnout,
    const void* __restrict__ mask, unsigned* __restrict__ mp,
    const float* __restrict__ Wq, const float* __restrict__ Wk,
    const float* __restrict__ Wv, const float* __restrict__ Wo,
    const float* __restrict__ W1, const float* __restrict__ W2,
    const float* __restrict__ bq, const float* __restrict__ bk,
    const float* __restrict__ bv,
    unsigned short* __restrict__ wqkv, unsigned short* __restrict__ wob,
    unsigned short* __restrict__ w1b, unsigned short* __restrict__ w2b,
    float* __restrict__ bqkv) {
  const int b = blockIdx.x;
  const int t = threadIdx.x;
  if (b < TT) {
    // ---- LayerNorm row ----
    const f32x4* xr = (const f32x4*)(x + (size_t)b * DM);
    f32x4 v = xr[t];
    float s = v[0] + v[1] + v[2] + v[3];
    float q = v[0]*v[0] + v[1]*v[1] + v[2]*v[2] + v[3]*v[3];
    #pragma unroll
    for (int off = 32; off >= 1; off >>= 1) { s += __shfl_xor(s, off); q += __shfl_xor(q, off); }
    __shared__ float red[8];
    int wv = t >> 6;
    if ((t & 63) == 0) { red[wv] = s; red[4 + wv] = q; }
    __syncthreads();
    s = red[0] + red[1] + red[2] + red[3];
    q = red[4] + red[5] + red[6] + red[7];
    float mu = s * (1.0f / DM);
    float var = q * (1.0f / DM) - mu * mu;
    float rs = rsqrtf(var + 1e-5f);
    f32x4 sv = ((const f32x4*)sc)[t], bv_ = ((const f32x4*)bi)[t];
    ushort4v o;
    #pragma unroll
    for (int j = 0; j < 4; ++j) o[j] = f2bf((v[j] - mu) * rs * sv[j] + bv_[j]);
    *(ushort4v*)(xnout + (size_t)b * DM + t * 4) = o;
  } else if (b < TT + 1024) {
    // ---- mask pack with self-detected dtype (same OR-scan as old prep) ----
    unsigned a = 0;
    const unsigned* mi4 = (const unsigned*)mask;
    for (int i = t; i < 4096; i += 256) a |= mi4[i];
    #pragma unroll
    for (int off = 32; off >= 1; off >>= 1) a |= __shfl_xor(a, off);
    __shared__ unsigned sh[4];
    if ((t & 63) == 0) sh[t >> 6] = a;
    __syncthreads();
    unsigned o = sh[0] | sh[1] | sh[2] | sh[3];
    const int cls = (o & 0xFEFEFEFEu) ? 2 : ((o & 0xFFFFFF00u) ? 1 : 0);
    int w = (b - TT) * 256 + t;   // word over B*L*(L/32) = 262144
    unsigned bits = 0u;
    if (cls == 1) {
      const unsigned char* mb = (const unsigned char*)mask + (size_t)w * 32;
      #pragma unroll 8
      for (int i = 0; i < 32; ++i) bits |= (mb[i] ? 1u : 0u) << i;
    } else {
      const unsigned* mi = (const unsigned*)mask + (size_t)w * 32;
      #pragma unroll 8
      for (int i = 0; i < 32; ++i) bits |= (mi[i] ? 1u : 0u) << i;
    }
    mp[w] = bits;
  } else if (b < TT + 1024 + 6144) {
    // ---- weight cvt fp32 -> bf16 ----
    int i = (b - TT - 1024) * 256 + t;
    const float* src; unsigned short* dst; int li;
    if (i < 131072)      { src = Wq; dst = wqkv;             li = i; }
    else if (i < 262144) { src = Wk; dst = wqkv + (1 << 20); li = i - 131072; }
    else if (i < 393216) { src = Wv; dst = wqkv + (2 << 20); li = i - 262144; }
    else if (i < 524288) { src = Wo; dst = wob;              li = i - 393216; }
    else if (i < 1048576){ src = W1; dst = w1b;              li = i - 524288; }
    else                 { src = W2; dst = w2b;              li = i - 1048576; }
    const f32x4* s4 = (const f32x4*)src;
    f32x4 a = s4[li * 2], c = s4[li * 2 + 1];
    short8 o;
    o[0] = (short)f2bf(a[0]); o[1] = (short)f2bf(a[1]);
    o[2] = (short)f2bf(a[2]); o[3] = (short)f2bf(a[3]);
    o[4] = (short)f2bf(c[0]); o[5] = (short)f2bf(c[1]);
    o[6] = (short)f2bf(c[2]); o[7] = (short)f2bf(c[3]);
    *(short8*)(dst + (size_t)li * 8) = o;
  } else {
    // ---- QKV bias concat ----
    int i = (b - TT - 1024 - 6144) * 256 + t;  // 3072
    bqkv[i] = (i < 1024) ? bq[i] : (i < 2048 ? bk[i - 1024] : bv[i - 2048]);
  }
}

// ---------- LayerNorm only (LN2) ----------
__global__ __launch_bounds__(256) void ln_kernel(const float* __restrict__ x,
                                                 const float* __restrict__ sc,
                                                 const float* __restrict__ bi,
                                                 unsigned short* __restrict__ out) {
  int row = blockIdx.x;
  int t = threadIdx.x;
  const f32x4* xr = (const f32x4*)(x + (size_t)row * DM);
  f32x4 v = xr[t];
  float s = v[0] + v[1] + v[2] + v[3];
  float q = v[0]*v[0] + v[1]*v[1] + v[2]*v[2] + v[3]*v[3];
  #pragma unroll
  for (int off = 32; off >= 1; off >>= 1) { s += __shfl_xor(s, off); q += __shfl_xor(q, off); }
  __shared__ float red[8];
  int wv = t >> 6;
  if ((t & 63) == 0) { red[wv] = s; red[4 + wv] = q; }
  __syncthreads();
  s = red[0] + red[1] + red[2] + red[3];
  q = red[4] + red[5] + red[6] + red[7];
  float mu = s * (1.0f / DM);
  float var = q * (1.0f / DM) - mu * mu;
  float rs = rsqrtf(var + 1e-5f);
  f32x4 sv = ((const f32x4*)sc)[t], bv = ((const f32x4*)bi)[t];
  ushort4v o;
  #pragma unroll
  for (int j = 0; j < 4; ++j) o[j] = f2bf((v[j] - mu) * rs * sv[j] + bv[j]);
  *(ushort4v*)(out + (size_t)row * DM + t * 4) = o;
}

// ---------- GEMM v9: 128x128, dbuf pipelined, 2 blocks/CU (round-0 proven) ---
// K=1024 regime verdict (rounds 1-4): the 256^2 8-phase template's verified
// gain at K=1024 is only ~+10% (m248), and both 8-phase ports measured BELOW
// this structure (722 vs 771 TF). Patch swizzle also hurt (FETCH 64.8->82MB).
// This is the round-0 exact structure: linear grid, x-fast (B-panel reuse).
template <int EPI>
__global__ __launch_bounds__(256, 2)
void gemm5(const unsigned short* __restrict__ A, const unsigned short* __restrict__ Bw,
           const float* __restrict__ bias, void* __restrict__ out0,
           void* __restrict__ out1, void* __restrict__ out2,
           const float* __restrict__ res, int N, int K) {
  __shared__ __align__(16) char smem[65536];  // 2 x 32KB
  const int t = threadIdx.x;
  const int w = t >> 6, ln = t & 63;
  const int wm = w >> 1, wn = w & 1;
  const int lg = ln >> 4, lc = ln & 15;
  const int m0 = blockIdx.x * 128, n0 = blockIdx.y * 128;
  const size_t rb = (size_t)K * 2;
  const int nk = K >> 6;

  const char* srcp[8];
  #pragma unroll
  for (int i = 0; i < 8; ++i) {
    int off = i * 4096 + t * 16;
    if (off < 16384) {
      int r = off >> 7, c = (off >> 4) & 7;
      srcp[i] = (const char*)A + (size_t)(m0 + r) * rb + ((c ^ (r & 7)) << 4);
    } else {
      int ob = off - 16384;
      int r = ob >> 7, c = (ob >> 4) & 7;
      srcp[i] = (const char*)Bw + (size_t)(n0 + r) * rb + ((c ^ (r & 7)) << 4);
    }
  }
  auto stage8 = [&](int tile) {
    char* db = smem + ((tile & 1) << 15) + t * 16;
    const size_t ko = (size_t)tile << 7;
    #pragma unroll
    for (int i = 0; i < 8; ++i) gload_lds16(srcp[i] + ko, db + i * 4096);
  };

  int aoff[4][2], boff[4][2];
  #pragma unroll
  for (int x_ = 0; x_ < 4; ++x_)
    #pragma unroll
    for (int kk = 0; kk < 2; ++kk) {
      int ra = wm * 64 + x_ * 16 + lc;
      aoff[x_][kk] = ra * 128 + (((kk * 4 + lg) ^ (ra & 7)) << 4);
      int rn = wn * 64 + x_ * 16 + lc;
      boff[x_][kk] = 16384 + rn * 128 + (((kk * 4 + lg) ^ (rn & 7)) << 4);
    }

  f32x4 acc[4][4] = {};

  stage8(0);
  for (int T = 0; T < nk; ++T) {
    if (T + 1 < nk) stage8(T + 1);
    if (T == nk - 1) { WAITVM(0); } else { WAITVM(8); }  // tile T landed
    BARRIER;
    const char* buf = smem + ((T & 1) << 15);
    short8 afr[4][2], bfr[4][2];
    #pragma unroll
    for (int ni = 0; ni < 4; ++ni) {
      bfr[ni][0] = *(const short8*)(buf + boff[ni][0]);
      bfr[ni][1] = *(const short8*)(buf + boff[ni][1]);
    }
    #pragma unroll
    for (int mi = 0; mi < 4; ++mi) {
      afr[mi][0] = *(const short8*)(buf + aoff[mi][0]);
      afr[mi][1] = *(const short8*)(buf + aoff[mi][1]);
    }
    __builtin_amdgcn_s_setprio(1);
    #pragma unroll
    for (int mi = 0; mi < 4; ++mi)
      #pragma unroll
      for (int ni = 0; ni < 4; ++ni) {
        acc[mi][ni] = MFMA16(afr[mi][0], bfr[ni][0], acc[mi][ni]);
        acc[mi][ni] = MFMA16(afr[mi][1], bfr[ni][1], acc[mi][ni]);
      }
    __builtin_amdgcn_s_setprio(0);
    WAITLGKM0;   // my reads of buf[T&1] retired
    BARRIER;     // ALL waves' reads retired -> stage(T+2) may overwrite it
  }
  __syncthreads();  // epilogue overlay safety

  const int colb = n0 + wn * 64 + lc;
  const int rowb = m0 + wm * 64 + lg * 4;
  if constexpr (EPI >= 2) {
    #pragma unroll
    for (int ni = 0; ni < 4; ++ni) {
      int col = colb + ni * 16;
      float bv = bias[col];
      #pragma unroll
      for (int mi = 0; mi < 4; ++mi)
        #pragma unroll
        for (int rr = 0; rr < 4; ++rr) {
          int row = rowb + mi * 16 + rr;
          float v = acc[mi][ni][rr] + bv;
          if constexpr (EPI == 2)
            ((float*)out0)[(size_t)row * N + col] = res[(size_t)row * N + col] + v;
          else
            ((float*)out0)[(size_t)row * N + col] += v;
        }
    }
  } else {
    short* sl = (short*)(smem + w * 9216);  // 4 x 9216 = 36KB <= 64KB
    const bool isV = (EPI == 0) && (n0 + wn * 64 >= 2048);
    #pragma unroll
    for (int ni = 0; ni < 4; ++ni) {
      float bv = bias[colb + ni * 16];
      #pragma unroll
      for (int mi = 0; mi < 4; ++mi)
        #pragma unroll
        for (int rr = 0; rr < 4; ++rr) {
          int row_l = mi * 16 + lg * 4 + rr;
          int col_l = ni * 16 + lc;
          float v = acc[mi][ni][rr] + bv;
          if constexpr (EPI == 1) {
            float u2 = v * v;
            float mexp = v * (-2.302206744f - 0.102953795f * u2);
            v = v / (1.0f + exp2f(mexp));
          }
          if (isV) sl[col_l * 72 + row_l] = (short)f2bf(v);
          else     sl[row_l * 72 + col_l] = (short)f2bf(v);
        }
    }
    const int s8 = ln >> 3, c8 = ln & 7;
    if constexpr (EPI == 0) {
      const int b_ = m0 >> 10;
      const int l0 = (m0 & 1023) + wm * 64;
      const int h_ = ((n0 + wn * 64) >> 6) & 15;
      const size_t bh = (size_t)(b_ * NH + h_);
      if (n0 + wn * 64 < 2048) {
        char* dst = (char*)((n0 + wn * 64 < 1024) ? out0 : out1) + (((bh << 10) + l0) << 7);
        #pragma unroll
        for (int j = 0; j < 8; ++j) {
          short8 v8 = *(const short8*)(sl + (j * 8 + s8) * 72 + c8 * 8);
          *(short8*)(dst + j * 1024 + ln * 16) = v8;
        }
      } else {
        char* dst = (char*)out2 + bh * 131072 + l0 * 2 + c8 * 16;
        #pragma unroll
        for (int j = 0; j < 8; ++j) {
          short8 v8 = *(const short8*)(sl + (j * 8 + s8) * 72 + c8 * 8);
          *(short8*)(dst + (size_t)(j * 8 + s8) * 2048) = v8;
        }
      }
    } else {
      char* dst = (char*)out0 + (size_t)(m0 + wm * 64) * ((size_t)N * 2) +
                  (size_t)(n0 + wn * 64) * 2 + c8 * 16;
      #pragma unroll
      for (int j = 0; j < 8; ++j) {
        short8 v8 = *(const short8*)(sl + (j * 8 + s8) * 72 + c8 * 8);
        *(short8*)(dst + (size_t)(j * 8 + s8) * ((size_t)N * 2)) = v8;
      }
    }
  }
}

// ---------- flash attention: counted-vmcnt dbuf + setprio MFMA clusters -----
// Round-5 (kept): counted WAITVM(2) instead of per-iter vmcnt(0) drains (-8us).
// Round-6: T5 s_setprio(1) around the QK and PV MFMA clusters -- proven +4-7%
// on attn (m191 regime: 3 blocks/CU at independent phases, scheduler favors
// the MFMA-entering wave over other blocks' staging waves).
__global__ __launch_bounds__(512) void attn_kernel(const unsigned short* __restrict__ Q,
                                                   const unsigned short* __restrict__ Kb,
                                                   const unsigned short* __restrict__ Vt,
                                                   const unsigned* __restrict__ mp,
                                                   unsigned short* __restrict__ ctx) {
  __shared__ __align__(16) char kv[2][16384];      // [K tile 8KB | V tile 8KB] x2
  __shared__ __align__(16) short plds[8][16][72];  // per-wave P tile, padded rows
  const int t = threadIdx.x, wv = t >> 6, ln = t & 63;
  const int bid = blockIdx.x;
  const int wg = (bid & 7) * 128 + (bid >> 3);     // XCD swizzle (grid 1024)
  const int qt = wg & 7, h_ = (wg >> 3) & 15, b_ = wg >> 7;
  const int bh = b_ * NH + h_;
  const int lg = ln >> 4, lc = ln & 15;
  const int qrow0 = qt * 128 + wv * 16;

  const unsigned short* qbase = Q + ((size_t)bh * LL + qrow0) * DK;
  short8 qf0 = *(const short8*)(qbase + (size_t)lc * DK + lg * 8);
  short8 qf1 = *(const short8*)(qbase + (size_t)lc * DK + 32 + lg * 8);

  short8 onesf;
  #pragma unroll
  for (int j = 0; j < 8; ++j) onesf[j] = (short)0x3F80;  // bf16 1.0

  f32x4 o[4] = {};
  f32x4 o_l = {};  // row sums via ones-column MFMA

  const char* kg = (const char*)(Kb + (size_t)bh * LL * DK);
  const char* vg = (const char*)(Vt + (size_t)bh * DK * LL);
  const int srow = ln >> 3;
  const int gc = (ln & 7) ^ srow;
  const char* ksrc = kg + (size_t)(wv * 8 + srow) * 128 + gc * 16;
  const char* vsrc = vg + (size_t)(wv * 8 + srow) * 2048 + gc * 16;

  const unsigned* mrow = mp + ((size_t)b_ * LL + qrow0) * 32;

  gload_lds16(ksrc, kv[0] + wv * 1024);
  gload_lds16(vsrc, kv[0] + 8192 + wv * 1024);
  __syncthreads();   // prologue: tile 0 landed (drains vmcnt)

  int cur = 0;
  for (int kt = 0; kt < 16; ++kt) {
    if (kt < 15) {
      gload_lds16(ksrc + (size_t)(kt + 1) * 8192, kv[cur ^ 1] + wv * 1024);
      gload_lds16(vsrc + (size_t)(kt + 1) * 128, kv[cur ^ 1] + 8192 + wv * 1024);
      WAITVM(2);   // previous tile's 2 loads landed; new 2 stay in flight
    } else {
      WAITVM(0);   // last tile: drain the final prefetch
    }
    BARRIER;       // all waves' stages landed -> kv[cur] complete
    const char* kb_ = kv[cur];
    const char* vb_ = kv[cur] + 8192;
    f32x4 s[4] = {};
    __builtin_amdgcn_s_setprio(1);
    #pragma unroll
    for (int c = 0; c < 4; ++c) {
      int row = c * 16 + lc;
      short8 k0 = *(const short8*)(kb_ + row * 128 + ((lg) ^ (row & 7)) * 16);
      short8 k1 = *(const short8*)(kb_ + row * 128 + ((4 + lg) ^ (row & 7)) * 16);
      s[c] = MFMA16(qf0, k0, s[c]);
      s[c] = MFMA16(qf1, k1, s[c]);
    }
    __builtin_amdgcn_s_setprio(0);
    unsigned wrd[4][2];
    #pragma unroll
    for (int r = 0; r < 4; ++r) {
      const unsigned* mr = mrow + (size_t)(lg * 4 + r) * 32 + kt * 2;
      wrd[r][0] = mr[0]; wrd[r][1] = mr[1];
    }
    #pragma unroll
    for (int c = 0; c < 4; ++c)
      #pragma unroll
      for (int r = 0; r < 4; ++r) {
        bool mk = (wrd[r][c >> 1] >> ((c & 1) * 16 + lc)) & 1;
        float p = mk ? 0.0f : exp2f(fmaf(s[c][r], 0.18033688011112f, -16.0f));
        plds[wv][lg * 4 + r][c * 16 + lc] = (short)f2bf(p);
      }
    __builtin_amdgcn_s_setprio(1);
    #pragma unroll
    for (int kk = 0; kk < 2; ++kk) {
      short8 pf = *(const short8*)&plds[wv][lc][kk * 32 + lg * 8];
      o_l = MFMA16(pf, onesf, o_l);
      #pragma unroll
      for (int dt = 0; dt < 4; ++dt) {
        int row = dt * 16 + lc;
        short8 vf = *(const short8*)(vb_ + row * 128 + ((kk * 4 + lg) ^ (row & 7)) * 16);
        o[dt] = MFMA16(pf, vf, o[dt]);
      }
    }
    __builtin_amdgcn_s_setprio(0);
    WAITLGKM0;     // my LDS reads of kv[cur] retired
    BARRIER;       // all waves done with kv[cur] -> next stage may overwrite
    cur ^= 1;
  }
  #pragma unroll
  for (int r = 0; r < 4; ++r) {
    float l = o_l[r];
    float inv = (l > 0.0f) ? 1.0f / l : 0.0f;
    size_t trow = (size_t)b_ * LL + qt * 128 + wv * 16 + lg * 4 + r;
    #pragma unroll
    for (int dt = 0; dt < 4; ++dt)
      ctx[trow * DM + h_ * 64 + dt * 16 + lc] = f2bf(o[dt][r] * inv);
  }
}

// ---------- launch ----------
extern "C" void kernel_launch(void* const* d_in, const int* in_sizes, int n_in,
                              void* d_out, int out_size, void* d_ws, size_t ws_size,
                              hipStream_t stream) {
  const float* x   = (const float*)d_in[0];
  const void*  msk = d_in[1];
  const float* Wq = (const float*)d_in[2],  *bq = (const float*)d_in[3];
  const float* Wk = (const float*)d_in[4],  *bk = (const float*)d_in[5];
  const float* Wv = (const float*)d_in[6],  *bv = (const float*)d_in[7];
  const float* Wo = (const float*)d_in[8],  *bo = (const float*)d_in[9];
  const float* l1s = (const float*)d_in[10], *l1b = (const float*)d_in[11];
  const float* l2s = (const float*)d_in[12], *l2b = (const float*)d_in[13];
  const float* W1 = (const float*)d_in[14], *b1 = (const float*)d_in[15];
  const float* W2 = (const float*)d_in[16], *b2 = (const float*)d_in[17];
  float* out = (float*)d_out;
  char* ws = (char*)d_ws;
  const size_t MB = 1u << 20;

  unsigned short* wqkv = (unsigned short*)(ws + 0 * MB);  // 6MB (Wq|Wk|Wv rows)
  unsigned short* wob = (unsigned short*)(ws + 6 * MB);   // 2MB
  unsigned short* w1b = (unsigned short*)(ws + 8 * MB);   // 8MB
  unsigned short* w2b = (unsigned short*)(ws + 16 * MB);  // 8MB
  unsigned short* xn  = (unsigned short*)(ws + 24 * MB);  // 16MB (reused as ctx)
  unsigned short* qb  = (unsigned short*)(ws + 40 * MB);  // 16MB (reused as xn2)
  unsigned short* kb  = (unsigned short*)(ws + 56 * MB);  // 16MB
  unsigned short* vtb = (unsigned short*)(ws + 72 * MB);  // 16MB
  unsigned*       mpk = (unsigned*)(ws + 88 * MB);        // 1MB
  float*          bqkv = (float*)(ws + 89 * MB);          // 12KB
  unsigned short* ctx = xn;
  unsigned short* xn2 = qb;
  unsigned short* hb  = (unsigned short*)(ws + 90 * MB);  // mchunk*4096*2

  int mchunk;
  size_t avail = (ws_size > 90 * MB) ? ws_size - 90 * MB : 0;
  if      (avail >= 64 * MB) mchunk = 8192;
  else if (avail >= 16 * MB) mchunk = 2048;
  else if (avail >= 4 * MB)  mchunk = 512;
  else                       mchunk = 256;

  // fused phase-1: LN1 + mask pack + weight cvt + bias concat (one launch)
  prep_ln1_kernel<<<TT + 1024 + 6144 + 12, 256, 0, stream>>>(
      x, l1s, l1b, xn, msk, mpk,
      Wq, Wk, Wv, Wo, W1, W2, bq, bk, bv,
      wqkv, wob, w1b, w2b, bqkv);

  // fused QKV projection (M=8192, N=3072, K=1024)
  gemm5<0><<<dim3(64, 24), 256, 0, stream>>>(xn, wqkv, bqkv, qb, kb, vtb,
                                             nullptr, 3072, DM);

  // attention (1024 blocks: 8 b * 16 h * 8 q-tiles of 128 rows)
  attn_kernel<<<1024, 512, 0, stream>>>(qb, kb, vtb, mpk, ctx);

  // Wo + residual -> d_out (fp32)
  gemm5<2><<<dim3(64, 8), 256, 0, stream>>>(ctx, wob, bo, out, nullptr, nullptr,
                                            x, DM, DM);

  // LN2
  ln_kernel<<<TT, 256, 0, stream>>>(out, l2s, l2b, xn2);

  // FFN, chunked over M to bound scratch
  for (int off = 0; off < TT; off += mchunk) {
    gemm5<1><<<dim3(mchunk / 128, 32), 256, 0, stream>>>(
        xn2 + (size_t)off * DM, w1b, b1, hb, nullptr, nullptr, nullptr, FF, DM);
    gemm5<3><<<dim3(mchunk / 128, 8), 256, 0, stream>>>(
        hb, w2b, b2, out + (size_t)off * DM, nullptr, nullptr, nullptr, DM, FF);
  }
}

// Round 7
// 375.361 us; speedup vs baseline: 1.0573x; 1.0130x over previous
//
#include <hip/hip_runtime.h>
#include <cstdint>
#include <cstddef>

// ---------- types ----------
typedef __attribute__((ext_vector_type(8))) short short8;     // 8 x bf16
typedef __attribute__((ext_vector_type(4))) float f32x4;
typedef __attribute__((ext_vector_type(4))) unsigned short ushort4v;
typedef __attribute__((ext_vector_type(2))) unsigned uint2v;

#define DEVI __device__ __forceinline__

DEVI unsigned short f2bf(float f) {  // RNE f32 -> bf16 bits
  union { float f; unsigned u; } x; x.f = f;
  unsigned r = x.u + 0x7fffu + ((x.u >> 16) & 1u);
  return (unsigned short)(r >> 16);
}

#define MFMA16(a, b, c) __builtin_amdgcn_mfma_f32_16x16x32_bf16(a, b, c, 0, 0, 0)
#define FENCE asm volatile("" ::: "memory")
#define WAITVM(n) asm volatile("s_waitcnt vmcnt(" #n ")" ::: "memory")
#define WAITLGKM0 asm volatile("s_waitcnt lgkmcnt(0)" ::: "memory")
#define BARRIER do { FENCE; __builtin_amdgcn_s_barrier(); FENCE; } while (0)

typedef __attribute__((address_space(1))) const void g_void;
typedef __attribute__((address_space(3))) void lds_void;
DEVI void gload_lds16(const void* g, void* l) {
  __builtin_amdgcn_global_load_lds((g_void*)g, (lds_void*)l, 16, 0, 0);
}

// ---------- constants ----------
static constexpr int DM = 1024;   // d_model
static constexpr int NH = 16;     // heads
static constexpr int DK = 64;     // head dim
static constexpr int FF = 4096;   // d_ff
static constexpr int BB = 8;      // batch
static constexpr int LL = 1024;   // seq
static constexpr int TT = BB * LL; // 8192 tokens

// ---------- fused phase-1: LN1 + mask-pack + weight cvt + bias concat -------
// Block map: [0,TT) LN rows | [TT,TT+1024) mask-pack | [+6144) weight cvt |
// [+12) bias concat. Pack blocks self-detect mask dtype via 16KB OR-scan.
__global__ __launch_bounds__(256) void prep_ln1_kernel(
    const float* __restrict__ x, const float* __restrict__ sc,
    const float* __restrict__ bi, unsigned short* __restrict__ xnout,
    const void* __restrict__ mask, unsigned* __restrict__ mp,
    const float* __restrict__ Wq, const float* __restrict__ Wk,
    const float* __restrict__ Wv, const float* __restrict__ Wo,
    const float* __restrict__ W1, const float* __restrict__ W2,
    const float* __restrict__ bq, const float* __restrict__ bk,
    const float* __restrict__ bv,
    unsigned short* __restrict__ wqkv, unsigned short* __restrict__ wob,
    unsigned short* __restrict__ w1b, unsigned short* __restrict__ w2b,
    float* __restrict__ bqkv) {
  const int b = blockIdx.x;
  const int t = threadIdx.x;
  if (b < TT) {
    // ---- LayerNorm row ----
    const f32x4* xr = (const f32x4*)(x + (size_t)b * DM);
    f32x4 v = xr[t];
    float s = v[0] + v[1] + v[2] + v[3];
    float q = v[0]*v[0] + v[1]*v[1] + v[2]*v[2] + v[3]*v[3];
    #pragma unroll
    for (int off = 32; off >= 1; off >>= 1) { s += __shfl_xor(s, off); q += __shfl_xor(q, off); }
    __shared__ float red[8];
    int wv = t >> 6;
    if ((t & 63) == 0) { red[wv] = s; red[4 + wv] = q; }
    __syncthreads();
    s = red[0] + red[1] + red[2] + red[3];
    q = red[4] + red[5] + red[6] + red[7];
    float mu = s * (1.0f / DM);
    float var = q * (1.0f / DM) - mu * mu;
    float rs = rsqrtf(var + 1e-5f);
    f32x4 sv = ((const f32x4*)sc)[t], bv_ = ((const f32x4*)bi)[t];
    ushort4v o;
    #pragma unroll
    for (int j = 0; j < 4; ++j) o[j] = f2bf((v[j] - mu) * rs * sv[j] + bv_[j]);
    *(ushort4v*)(xnout + (size_t)b * DM + t * 4) = o;
  } else if (b < TT + 1024) {
    // ---- mask pack with self-detected dtype ----
    unsigned a = 0;
    const unsigned* mi4 = (const unsigned*)mask;
    for (int i = t; i < 4096; i += 256) a |= mi4[i];
    #pragma unroll
    for (int off = 32; off >= 1; off >>= 1) a |= __shfl_xor(a, off);
    __shared__ unsigned sh[4];
    if ((t & 63) == 0) sh[t >> 6] = a;
    __syncthreads();
    unsigned o = sh[0] | sh[1] | sh[2] | sh[3];
    const int cls = (o & 0xFEFEFEFEu) ? 2 : ((o & 0xFFFFFF00u) ? 1 : 0);
    int w = (b - TT) * 256 + t;   // word over B*L*(L/32) = 262144
    unsigned bits = 0u;
    if (cls == 1) {
      const unsigned char* mb = (const unsigned char*)mask + (size_t)w * 32;
      #pragma unroll 8
      for (int i = 0; i < 32; ++i) bits |= (mb[i] ? 1u : 0u) << i;
    } else {
      const unsigned* mi = (const unsigned*)mask + (size_t)w * 32;
      #pragma unroll 8
      for (int i = 0; i < 32; ++i) bits |= (mi[i] ? 1u : 0u) << i;
    }
    mp[w] = bits;
  } else if (b < TT + 1024 + 6144) {
    // ---- weight cvt fp32 -> bf16 ----
    int i = (b - TT - 1024) * 256 + t;
    const float* src; unsigned short* dst; int li;
    if (i < 131072)      { src = Wq; dst = wqkv;             li = i; }
    else if (i < 262144) { src = Wk; dst = wqkv + (1 << 20); li = i - 131072; }
    else if (i < 393216) { src = Wv; dst = wqkv + (2 << 20); li = i - 262144; }
    else if (i < 524288) { src = Wo; dst = wob;              li = i - 393216; }
    else if (i < 1048576){ src = W1; dst = w1b;              li = i - 524288; }
    else                 { src = W2; dst = w2b;              li = i - 1048576; }
    const f32x4* s4 = (const f32x4*)src;
    f32x4 a = s4[li * 2], c = s4[li * 2 + 1];
    short8 o;
    o[0] = (short)f2bf(a[0]); o[1] = (short)f2bf(a[1]);
    o[2] = (short)f2bf(a[2]); o[3] = (short)f2bf(a[3]);
    o[4] = (short)f2bf(c[0]); o[5] = (short)f2bf(c[1]);
    o[6] = (short)f2bf(c[2]); o[7] = (short)f2bf(c[3]);
    *(short8*)(dst + (size_t)li * 8) = o;
  } else {
    // ---- QKV bias concat ----
    int i = (b - TT - 1024 - 6144) * 256 + t;  // 3072
    bqkv[i] = (i < 1024) ? bq[i] : (i < 2048 ? bk[i - 1024] : bv[i - 2048]);
  }
}

// ---------- LayerNorm only (LN2) ----------
__global__ __launch_bounds__(256) void ln_kernel(const float* __restrict__ x,
                                                 const float* __restrict__ sc,
                                                 const float* __restrict__ bi,
                                                 unsigned short* __restrict__ out) {
  int row = blockIdx.x;
  int t = threadIdx.x;
  const f32x4* xr = (const f32x4*)(x + (size_t)row * DM);
  f32x4 v = xr[t];
  float s = v[0] + v[1] + v[2] + v[3];
  float q = v[0]*v[0] + v[1]*v[1] + v[2]*v[2] + v[3]*v[3];
  #pragma unroll
  for (int off = 32; off >= 1; off >>= 1) { s += __shfl_xor(s, off); q += __shfl_xor(q, off); }
  __shared__ float red[8];
  int wv = t >> 6;
  if ((t & 63) == 0) { red[wv] = s; red[4 + wv] = q; }
  __syncthreads();
  s = red[0] + red[1] + red[2] + red[3];
  q = red[4] + red[5] + red[6] + red[7];
  float mu = s * (1.0f / DM);
  float var = q * (1.0f / DM) - mu * mu;
  float rs = rsqrtf(var + 1e-5f);
  f32x4 sv = ((const f32x4*)sc)[t], bv = ((const f32x4*)bi)[t];
  ushort4v o;
  #pragma unroll
  for (int j = 0; j < 4; ++j) o[j] = f2bf((v[j] - mu) * rs * sv[j] + bv[j]);
  *(ushort4v*)(out + (size_t)row * DM + t * 4) = o;
}

// ---------- GEMM v9: 128x128, dbuf pipelined, 2 blocks/CU (round-0 proven) ---
// K=1024 regime verdict (rounds 1-4): the 256^2 8-phase template's verified
// gain at K=1024 is only ~+10% (m248), and both 8-phase ports measured BELOW
// this structure (722 vs 771 TF). Patch swizzle also hurt (FETCH 64.8->82MB).
// This is the round-0 exact structure: linear grid, x-fast (B-panel reuse).
template <int EPI>
__global__ __launch_bounds__(256, 2)
void gemm5(const unsigned short* __restrict__ A, const unsigned short* __restrict__ Bw,
           const float* __restrict__ bias, void* __restrict__ out0,
           void* __restrict__ out1, void* __restrict__ out2,
           const float* __restrict__ res, int N, int K) {
  __shared__ __align__(16) char smem[65536];  // 2 x 32KB
  const int t = threadIdx.x;
  const int w = t >> 6, ln = t & 63;
  const int wm = w >> 1, wn = w & 1;
  const int lg = ln >> 4, lc = ln & 15;
  const int m0 = blockIdx.x * 128, n0 = blockIdx.y * 128;
  const size_t rb = (size_t)K * 2;
  const int nk = K >> 6;

  const char* srcp[8];
  #pragma unroll
  for (int i = 0; i < 8; ++i) {
    int off = i * 4096 + t * 16;
    if (off < 16384) {
      int r = off >> 7, c = (off >> 4) & 7;
      srcp[i] = (const char*)A + (size_t)(m0 + r) * rb + ((c ^ (r & 7)) << 4);
    } else {
      int ob = off - 16384;
      int r = ob >> 7, c = (ob >> 4) & 7;
      srcp[i] = (const char*)Bw + (size_t)(n0 + r) * rb + ((c ^ (r & 7)) << 4);
    }
  }
  auto stage8 = [&](int tile) {
    char* db = smem + ((tile & 1) << 15) + t * 16;
    const size_t ko = (size_t)tile << 7;
    #pragma unroll
    for (int i = 0; i < 8; ++i) gload_lds16(srcp[i] + ko, db + i * 4096);
  };

  int aoff[4][2], boff[4][2];
  #pragma unroll
  for (int x_ = 0; x_ < 4; ++x_)
    #pragma unroll
    for (int kk = 0; kk < 2; ++kk) {
      int ra = wm * 64 + x_ * 16 + lc;
      aoff[x_][kk] = ra * 128 + (((kk * 4 + lg) ^ (ra & 7)) << 4);
      int rn = wn * 64 + x_ * 16 + lc;
      boff[x_][kk] = 16384 + rn * 128 + (((kk * 4 + lg) ^ (rn & 7)) << 4);
    }

  f32x4 acc[4][4] = {};

  stage8(0);
  for (int T = 0; T < nk; ++T) {
    if (T + 1 < nk) stage8(T + 1);
    if (T == nk - 1) { WAITVM(0); } else { WAITVM(8); }  // tile T landed
    BARRIER;
    const char* buf = smem + ((T & 1) << 15);
    short8 afr[4][2], bfr[4][2];
    #pragma unroll
    for (int ni = 0; ni < 4; ++ni) {
      bfr[ni][0] = *(const short8*)(buf + boff[ni][0]);
      bfr[ni][1] = *(const short8*)(buf + boff[ni][1]);
    }
    #pragma unroll
    for (int mi = 0; mi < 4; ++mi) {
      afr[mi][0] = *(const short8*)(buf + aoff[mi][0]);
      afr[mi][1] = *(const short8*)(buf + aoff[mi][1]);
    }
    __builtin_amdgcn_s_setprio(1);
    #pragma unroll
    for (int mi = 0; mi < 4; ++mi)
      #pragma unroll
      for (int ni = 0; ni < 4; ++ni) {
        acc[mi][ni] = MFMA16(afr[mi][0], bfr[ni][0], acc[mi][ni]);
        acc[mi][ni] = MFMA16(afr[mi][1], bfr[ni][1], acc[mi][ni]);
      }
    __builtin_amdgcn_s_setprio(0);
    WAITLGKM0;   // my reads of buf[T&1] retired
    BARRIER;     // ALL waves' reads retired -> stage(T+2) may overwrite it
  }
  __syncthreads();  // epilogue overlay safety

  const int colb = n0 + wn * 64 + lc;
  const int rowb = m0 + wm * 64 + lg * 4;
  if constexpr (EPI >= 2) {
    #pragma unroll
    for (int ni = 0; ni < 4; ++ni) {
      int col = colb + ni * 16;
      float bv = bias[col];
      #pragma unroll
      for (int mi = 0; mi < 4; ++mi)
        #pragma unroll
        for (int rr = 0; rr < 4; ++rr) {
          int row = rowb + mi * 16 + rr;
          float v = acc[mi][ni][rr] + bv;
          if constexpr (EPI == 2)
            ((float*)out0)[(size_t)row * N + col] = res[(size_t)row * N + col] + v;
          else
            ((float*)out0)[(size_t)row * N + col] += v;
        }
    }
  } else {
    short* sl = (short*)(smem + w * 9216);  // 4 x 9216 = 36KB <= 64KB
    const bool isV = (EPI == 0) && (n0 + wn * 64 >= 2048);
    #pragma unroll
    for (int ni = 0; ni < 4; ++ni) {
      float bv = bias[colb + ni * 16];
      #pragma unroll
      for (int mi = 0; mi < 4; ++mi)
        #pragma unroll
        for (int rr = 0; rr < 4; ++rr) {
          int row_l = mi * 16 + lg * 4 + rr;
          int col_l = ni * 16 + lc;
          float v = acc[mi][ni][rr] + bv;
          if constexpr (EPI == 1) {
            float u2 = v * v;
            float mexp = v * (-2.302206744f - 0.102953795f * u2);
            v = v / (1.0f + exp2f(mexp));
          }
          if (isV) sl[col_l * 72 + row_l] = (short)f2bf(v);
          else     sl[row_l * 72 + col_l] = (short)f2bf(v);
        }
    }
    const int s8 = ln >> 3, c8 = ln & 7;
    if constexpr (EPI == 0) {
      const int b_ = m0 >> 10;
      const int l0 = (m0 & 1023) + wm * 64;
      const int h_ = ((n0 + wn * 64) >> 6) & 15;
      const size_t bh = (size_t)(b_ * NH + h_);
      if (n0 + wn * 64 < 2048) {
        char* dst = (char*)((n0 + wn * 64 < 1024) ? out0 : out1) + (((bh << 10) + l0) << 7);
        #pragma unroll
        for (int j = 0; j < 8; ++j) {
          short8 v8 = *(const short8*)(sl + (j * 8 + s8) * 72 + c8 * 8);
          *(short8*)(dst + j * 1024 + ln * 16) = v8;
        }
      } else {
        char* dst = (char*)out2 + bh * 131072 + l0 * 2 + c8 * 16;
        #pragma unroll
        for (int j = 0; j < 8; ++j) {
          short8 v8 = *(const short8*)(sl + (j * 8 + s8) * 72 + c8 * 8);
          *(short8*)(dst + (size_t)(j * 8 + s8) * 2048) = v8;
        }
      }
    } else {
      char* dst = (char*)out0 + (size_t)(m0 + wm * 64) * ((size_t)N * 2) +
                  (size_t)(n0 + wn * 64) * 2 + c8 * 16;
      #pragma unroll
      for (int j = 0; j < 8; ++j) {
        short8 v8 = *(const short8*)(sl + (j * 8 + s8) * 72 + c8 * 8);
        *(short8*)(dst + (size_t)(j * 8 + s8) * ((size_t)N * 2)) = v8;
      }
    }
  }
}

// ---------- flash attention: swapped-QK^T softmax (round-7) -----------------
// Round-5 (kept): counted WAITVM(2) vs per-iter vmcnt(0) drains (-8us).
// Round-6 (kept): setprio(1) around MFMA clusters.
// Round-7: softmax was VALU-bound (~300 cyc/kt vs ~90 cyc MFMA). A and B
// MFMA fragments have identical layouts, so MFMA16(k,q) instead of
// MFMA16(q,k) computes S^T with ZERO load changes. Lane then owns, for its
// own q-row (=lc), 4 CONSECUTIVE k per c-block -> P-store becomes
// 8 v_cvt_pk_bf16_f32 + 4 ds_write_b64 (was 16 manual-RNE f2bf + 16
// scattered ds_write_b16), and mask fetch drops 8 dwords -> 2 per lane/kt
// (q-row now lane-local). PV read pattern plds[lc][k] is untouched.
__global__ __launch_bounds__(512) void attn_kernel(const unsigned short* __restrict__ Q,
                                                   const unsigned short* __restrict__ Kb,
                                                   const unsigned short* __restrict__ Vt,
                                                   const unsigned* __restrict__ mp,
                                                   unsigned short* __restrict__ ctx) {
  __shared__ __align__(16) char kv[2][16384];      // [K tile 8KB | V tile 8KB] x2
  __shared__ __align__(16) short plds[8][16][72];  // per-wave P tile [q=16][k=64+pad]
  const int t = threadIdx.x, wv = t >> 6, ln = t & 63;
  const int bid = blockIdx.x;
  const int wg = (bid & 7) * 128 + (bid >> 3);     // XCD swizzle (grid 1024)
  const int qt = wg & 7, h_ = (wg >> 3) & 15, b_ = wg >> 7;
  const int bh = b_ * NH + h_;
  const int lg = ln >> 4, lc = ln & 15;
  const int lg4 = lg * 4;
  const int qrow0 = qt * 128 + wv * 16;

  const unsigned short* qbase = Q + ((size_t)bh * LL + qrow0) * DK;
  short8 qf0 = *(const short8*)(qbase + (size_t)lc * DK + lg * 8);
  short8 qf1 = *(const short8*)(qbase + (size_t)lc * DK + 32 + lg * 8);

  short8 onesf;
  #pragma unroll
  for (int j = 0; j < 8; ++j) onesf[j] = (short)0x3F80;  // bf16 1.0

  f32x4 o[4] = {};
  f32x4 o_l = {};  // row sums via ones-column MFMA

  const char* kg = (const char*)(Kb + (size_t)bh * LL * DK);
  const char* vg = (const char*)(Vt + (size_t)bh * DK * LL);
  const int srow = ln >> 3;
  const int gc = (ln & 7) ^ srow;
  const char* ksrc = kg + (size_t)(wv * 8 + srow) * 128 + gc * 16;
  const char* vsrc = vg + (size_t)(wv * 8 + srow) * 2048 + gc * 16;

  // per-lane mask row: this lane's q-row = qrow0 + lc (32 words per row)
  const unsigned* mrow = mp + ((size_t)b_ * LL + qrow0 + lc) * 32;

  gload_lds16(ksrc, kv[0] + wv * 1024);
  gload_lds16(vsrc, kv[0] + 8192 + wv * 1024);
  __syncthreads();   // prologue: tile 0 landed (drains vmcnt)

  int cur = 0;
  for (int kt = 0; kt < 16; ++kt) {
    if (kt < 15) {
      gload_lds16(ksrc + (size_t)(kt + 1) * 8192, kv[cur ^ 1] + wv * 1024);
      gload_lds16(vsrc + (size_t)(kt + 1) * 128, kv[cur ^ 1] + 8192 + wv * 1024);
      WAITVM(2);   // previous tile's 2 loads landed; new 2 stay in flight
    } else {
      WAITVM(0);   // last tile: drain the final prefetch
    }
    BARRIER;       // all waves' stages landed -> kv[cur] complete
    const char* kb_ = kv[cur];
    const char* vb_ = kv[cur] + 8192;
    const unsigned w0 = mrow[kt * 2], w1 = mrow[kt * 2 + 1];
    f32x4 s[4] = {};
    __builtin_amdgcn_s_setprio(1);
    #pragma unroll
    for (int c = 0; c < 4; ++c) {
      int row = c * 16 + lc;
      short8 k0 = *(const short8*)(kb_ + row * 128 + ((lg) ^ (row & 7)) * 16);
      short8 k1 = *(const short8*)(kb_ + row * 128 + ((4 + lg) ^ (row & 7)) * 16);
      s[c] = MFMA16(k0, qf0, s[c]);   // SWAPPED: S^T[k=c*16+lg4+r][q=lc]
      s[c] = MFMA16(k1, qf1, s[c]);
    }
    __builtin_amdgcn_s_setprio(0);
    #pragma unroll
    for (int c = 0; c < 4; ++c) {
      const unsigned wsel = (c >= 2) ? w1 : w0;
      float p[4];
      #pragma unroll
      for (int r = 0; r < 4; ++r) {
        bool mk = (wsel >> ((c & 1) * 16 + lg4 + r)) & 1;
        p[r] = mk ? 0.0f : exp2f(fmaf(s[c][r], 0.18033688011112f, -16.0f));
      }
      unsigned plo, phi;
      asm("v_cvt_pk_bf16_f32 %0, %1, %2" : "=v"(plo) : "v"(p[0]), "v"(p[1]));
      asm("v_cvt_pk_bf16_f32 %0, %1, %2" : "=v"(phi) : "v"(p[2]), "v"(p[3]));
      uint2v pk; pk[0] = plo; pk[1] = phi;
      *(uint2v*)&plds[wv][lc][c * 16 + lg4] = pk;   // 4 consecutive k, b64
    }
    __builtin_amdgcn_s_setprio(1);
    #pragma unroll
    for (int kk = 0; kk < 2; ++kk) {
      short8 pf = *(const short8*)&plds[wv][lc][kk * 32 + lg * 8];
      o_l = MFMA16(pf, onesf, o_l);
      #pragma unroll
      for (int dt = 0; dt < 4; ++dt) {
        int row = dt * 16 + lc;
        short8 vf = *(const short8*)(vb_ + row * 128 + ((kk * 4 + lg) ^ (row & 7)) * 16);
        o[dt] = MFMA16(pf, vf, o[dt]);
      }
    }
    __builtin_amdgcn_s_setprio(0);
    WAITLGKM0;     // my LDS reads of kv[cur] retired
    BARRIER;       // all waves done with kv[cur] -> next stage may overwrite
    cur ^= 1;
  }
  #pragma unroll
  for (int r = 0; r < 4; ++r) {
    float l = o_l[r];
    float inv = (l > 0.0f) ? 1.0f / l : 0.0f;
    size_t trow = (size_t)b_ * LL + qt * 128 + wv * 16 + lg * 4 + r;
    #pragma unroll
    for (int dt = 0; dt < 4; ++dt)
      ctx[trow * DM + h_ * 64 + dt * 16 + lc] = f2bf(o[dt][r] * inv);
  }
}

// ---------- launch ----------
extern "C" void kernel_launch(void* const* d_in, const int* in_sizes, int n_in,
                              void* d_out, int out_size, void* d_ws, size_t ws_size,
                              hipStream_t stream) {
  const float* x   = (const float*)d_in[0];
  const void*  msk = d_in[1];
  const float* Wq = (const float*)d_in[2],  *bq = (const float*)d_in[3];
  const float* Wk = (const float*)d_in[4],  *bk = (const float*)d_in[5];
  const float* Wv = (const float*)d_in[6],  *bv = (const float*)d_in[7];
  const float* Wo = (const float*)d_in[8],  *bo = (const float*)d_in[9];
  const float* l1s = (const float*)d_in[10], *l1b = (const float*)d_in[11];
  const float* l2s = (const float*)d_in[12], *l2b = (const float*)d_in[13];
  const float* W1 = (const float*)d_in[14], *b1 = (const float*)d_in[15];
  const float* W2 = (const float*)d_in[16], *b2 = (const float*)d_in[17];
  float* out = (float*)d_out;
  char* ws = (char*)d_ws;
  const size_t MB = 1u << 20;

  unsigned short* wqkv = (unsigned short*)(ws + 0 * MB);  // 6MB (Wq|Wk|Wv rows)
  unsigned short* wob = (unsigned short*)(ws + 6 * MB);   // 2MB
  unsigned short* w1b = (unsigned short*)(ws + 8 * MB);   // 8MB
  unsigned short* w2b = (unsigned short*)(ws + 16 * MB);  // 8MB
  unsigned short* xn  = (unsigned short*)(ws + 24 * MB);  // 16MB (reused as ctx)
  unsigned short* qb  = (unsigned short*)(ws + 40 * MB);  // 16MB (reused as xn2)
  unsigned short* kb  = (unsigned short*)(ws + 56 * MB);  // 16MB
  unsigned short* vtb = (unsigned short*)(ws + 72 * MB);  // 16MB
  unsigned*       mpk = (unsigned*)(ws + 88 * MB);        // 1MB
  float*          bqkv = (float*)(ws + 89 * MB);          // 12KB
  unsigned short* ctx = xn;
  unsigned short* xn2 = qb;
  unsigned short* hb  = (unsigned short*)(ws + 90 * MB);  // mchunk*4096*2

  int mchunk;
  size_t avail = (ws_size > 90 * MB) ? ws_size - 90 * MB : 0;
  if      (avail >= 64 * MB) mchunk = 8192;
  else if (avail >= 16 * MB) mchunk = 2048;
  else if (avail >= 4 * MB)  mchunk = 512;
  else                       mchunk = 256;

  // fused phase-1: LN1 + mask pack + weight cvt + bias concat (one launch)
  prep_ln1_kernel<<<TT + 1024 + 6144 + 12, 256, 0, stream>>>(
      x, l1s, l1b, xn, msk, mpk,
      Wq, Wk, Wv, Wo, W1, W2, bq, bk, bv,
      wqkv, wob, w1b, w2b, bqkv);

  // fused QKV projection (M=8192, N=3072, K=1024)
  gemm5<0><<<dim3(64, 24), 256, 0, stream>>>(xn, wqkv, bqkv, qb, kb, vtb,
                                             nullptr, 3072, DM);

  // attention (1024 blocks: 8 b * 16 h * 8 q-tiles of 128 rows)
  attn_kernel<<<1024, 512, 0, stream>>>(qb, kb, vtb, mpk, ctx);

  // Wo + residual -> d_out (fp32)
  gemm5<2><<<dim3(64, 8), 256, 0, stream>>>(ctx, wob, bo, out, nullptr, nullptr,
                                            x, DM, DM);

  // LN2
  ln_kernel<<<TT, 256, 0, stream>>>(out, l2s, l2b, xn2);

  // FFN, chunked over M to bound scratch
  for (int off = 0; off < TT; off += mchunk) {
    gemm5<1><<<dim3(mchunk / 128, 32), 256, 0, stream>>>(
        xn2 + (size_t)off * DM, w1b, b1, hb, nullptr, nullptr, nullptr, FF, DM);
    gemm5<3><<<dim3(mchunk / 128, 8), 256, 0, stream>>>(
        hb, w2b, b2, out + (size_t)off * DM, nullptr, nullptr, nullptr, DM, FF);
  }
}